// Round 1
// baseline (2711.603 us; speedup 1.0000x reference)
//
#include <hip/hip_runtime.h>
#include <math.h>

#define N_N 8000
#define N_E 12000
#define N_A 48000
#define N_B 64
#define N_H 64
#define N_DH 4096

__device__ __forceinline__ float atomAddF(float* p, float v) {
  return __hip_atomic_fetch_add(p, v, __ATOMIC_RELAXED, __HIP_MEMORY_SCOPE_AGENT);
}
__device__ __forceinline__ float sigm(float x) { return 1.f / (1.f + expf(-x)); }

// ---------------- setup kernels ----------------

// x0 = relu(node_attribute @ projW + projb); wave per node, lane = out-dim
__global__ void k_proj(const float* __restrict__ na, const float* __restrict__ W,
                       const float* __restrict__ b, float* __restrict__ x0) {
  int wid = (blockIdx.x * blockDim.x + threadIdx.x) >> 6;
  int lane = threadIdx.x & 63;
  if (wid >= N_N) return;
  const float* row = na + (size_t)wid * 110;
  float acc = b[lane];
  for (int k = 0; k < 110; ++k) acc = fmaf(row[k], W[k * 64 + lane], acc);
  x0[(size_t)wid * 64 + lane] = fmaxf(acc, 0.f);
}

// edge_feat[e] = [edge_attribute(8) | rbf(edge_length, K=8, cutoff=4)]
__global__ void k_edgefeat(const float* __restrict__ ea, const float* __restrict__ el,
                           float* __restrict__ ef) {
  int e = blockIdx.x * blockDim.x + threadIdx.x;
  if (e >= N_E) return;
  float x = el[e];
  const float g2 = (7.f / 4.f) * (7.f / 4.f);
#pragma unroll
  for (int j = 0; j < 8; ++j) ef[e * 16 + j] = ea[e * 8 + j];
#pragma unroll
  for (int j = 0; j < 8; ++j) {
    float d = x - j * (4.f / 7.f);
    ef[e * 16 + 8 + j] = expf(-g2 * d * d);
  }
}

// ee_feat[a] = [rbf(angle, 8, pi) | rbf(edge_length[angle_src], 8, 4)]
__global__ void k_anglefeat(const float* __restrict__ ang, const float* __restrict__ el,
                            const int* __restrict__ asrc, float* __restrict__ ee) {
  int a = blockIdx.x * blockDim.x + threadIdx.x;
  if (a >= N_A) return;
  const float PIf = 3.14159265358979323846f;
  float x = ang[a];
  float g1 = (7.f / PIf) * (7.f / PIf);
#pragma unroll
  for (int j = 0; j < 8; ++j) {
    float d = x - j * (PIf / 7.f);
    ee[a * 16 + j] = expf(-g1 * d * d);
  }
  float y = el[asrc[a]];
  float g2 = (7.f / 4.f) * (7.f / 4.f);
#pragma unroll
  for (int j = 0; j < 8; ++j) {
    float d = y - j * (4.f / 7.f);
    ee[a * 16 + 8 + j] = expf(-g2 * d * d);
  }
}

// W[R][C] -> WT[C][R]
__global__ void k_transpose(const float* __restrict__ W, float* __restrict__ WT,
                            int R, int C) {
  int idx = blockIdx.x * blockDim.x + threadIdx.x;
  if (idx >= R * C) return;
  int r = idx / C, c = idx % C;
  WT[c * R + r] = W[idx];
}

__global__ void k_bounds(const int* __restrict__ gid, int* __restrict__ gstart,
                         int* __restrict__ gend) {
  int n = blockIdx.x * blockDim.x + threadIdx.x;
  if (n >= N_N) return;
  int g = gid[n];
  atomicMin(&gstart[g], n);
  atomicMax(&gend[g], n + 1);
}

// ---------------- step kernels ----------------

// out[e] = relu(h[src[e]] @ W + b) (+ amsg[e] if ADD_AMSG); wave per edge, lane = o
template <bool ADD_AMSG>
__global__ void k_edge_mlp(const float* __restrict__ h, const int* __restrict__ src,
                           const float* __restrict__ W, const float* __restrict__ bias,
                           const float* __restrict__ amsg, float* __restrict__ out) {
  int wid = (blockIdx.x * blockDim.x + threadIdx.x) >> 6;
  int lane = threadIdx.x & 63;
  if (wid >= N_E) return;
  const float* hrow = h + (size_t)src[wid] * 64;
  float acc = bias[lane];
#pragma unroll
  for (int i = 0; i < 64; ++i) acc = fmaf(hrow[i], W[i * 64 + lane], acc);
  acc = fmaxf(acc, 0.f);
  if (ADD_AMSG) acc += amsg[(size_t)wid * 64 + lane];
  out[(size_t)wid * 64 + lane] = acc;
}

// Per-item rank-16 contraction + scatter:
//   m[item,o] = sum_{k<16} feat[item,k] * sum_i v[vi,i]*W[k,i,o]  + sum_i v[vi,i]*b2[i,o]
//   atomicAdd(out[dst[item]*64 + o], m[item,o])
// thread = item, blockIdx.y = o-chunk of 16. W reads are wave-uniform -> s_load.
template <bool GATHER>
__global__ void k_item_mm(const float* __restrict__ v, const int* __restrict__ src,
                          const float* __restrict__ feat, const float* __restrict__ W,
                          const float* __restrict__ b2, const int* __restrict__ dst,
                          float* __restrict__ out, int T) {
  int item = blockIdx.x * blockDim.x + threadIdx.x;
  int oc = blockIdx.y;  // 0..3
  bool act = item < T;
  int it2 = act ? item : 0;
  int vi = GATHER ? src[it2] : it2;
  float vv[64];
  const float4* vr = (const float4*)(v + (size_t)vi * 64);
#pragma unroll
  for (int q = 0; q < 16; ++q) {
    float4 t4 = vr[q];
    vv[4 * q + 0] = t4.x; vv[4 * q + 1] = t4.y;
    vv[4 * q + 2] = t4.z; vv[4 * q + 3] = t4.w;
  }
  float acc[16];
#pragma unroll
  for (int oo = 0; oo < 16; ++oo) acc[oo] = 0.f;
  const float* fr = feat + (size_t)it2 * 16;
  for (int k = 0; k < 17; ++k) {
    float fk = (k < 16) ? fr[k] : 1.f;
    const float* Wko = ((k < 16) ? (W + (size_t)k * 4096) : b2) + oc * 16;
#pragma unroll
    for (int i = 0; i < 64; ++i) {
      float t = fk * vv[i];
#pragma unroll
      for (int oo = 0; oo < 16; ++oo)
        acc[oo] = fmaf(t, Wko[i * 64 + oo], acc[oo]);
    }
  }
  if (act) {
    float* op = out + (size_t)dst[item] * 64 + oc * 16;
#pragma unroll
    for (int oo = 0; oo < 16; ++oo) atomAddF(op + oo, acc[oo]);
  }
}

// fused: x = relu(nacc + gnn_b); h' = GRU(x, h). wave per node, lane = unit
__global__ void k_gru(const float* __restrict__ nacc, const float* __restrict__ gnnb,
                      const float* __restrict__ h, const float* __restrict__ WihT,
                      const float* __restrict__ WhhT, const float* __restrict__ bih,
                      const float* __restrict__ bhh, float* __restrict__ hout) {
  int wid = (blockIdx.x * blockDim.x + threadIdx.x) >> 6;
  int lane = threadIdx.x & 63;
  if (wid >= N_N) return;
  const float* xr = nacc + (size_t)wid * 64;
  const float* hr = h + (size_t)wid * 64;
  float air = bih[lane], aiz = bih[64 + lane], ain = bih[128 + lane];
  float ahr = bhh[lane], ahz = bhh[64 + lane], ahn = bhh[128 + lane];
#pragma unroll 8
  for (int i = 0; i < 64; ++i) {
    float xi = fmaxf(xr[i] + gnnb[i], 0.f);
    float hi = hr[i];
    air = fmaf(xi, WihT[i * 192 + lane], air);
    aiz = fmaf(xi, WihT[i * 192 + 64 + lane], aiz);
    ain = fmaf(xi, WihT[i * 192 + 128 + lane], ain);
    ahr = fmaf(hi, WhhT[i * 192 + lane], ahr);
    ahz = fmaf(hi, WhhT[i * 192 + 64 + lane], ahz);
    ahn = fmaf(hi, WhhT[i * 192 + 128 + lane], ahn);
  }
  float r = sigm(air + ahr);
  float z = sigm(aiz + ahz);
  float n = tanhf(ain + r * ahn);
  hout[(size_t)wid * 64 + lane] = (1.f - z) * n + z * hr[lane];
}

__global__ void k_agg(const float* __restrict__ h, const float* __restrict__ x0,
                      float* __restrict__ agg) {
  int idx = blockIdx.x * blockDim.x + threadIdx.x;
  if (idx >= N_N * 64) return;
  int n = idx >> 6, d = idx & 63;
  agg[(size_t)n * 128 + d] = h[idx];
  agg[(size_t)n * 128 + 64 + d] = x0[idx];
}

// ---------------- Set2Set ----------------

// thread = (b, u): computes all 4 gates for unit u; xdim = 256 (lstm0) or 128 (lstm1)
__global__ void k_lstm(const float* __restrict__ x, int xdim,
                       const float* __restrict__ hin, const float* __restrict__ cin,
                       const float* __restrict__ Wih, const float* __restrict__ Whh,
                       const float* __restrict__ bih, const float* __restrict__ bhh,
                       float* __restrict__ hout, float* __restrict__ cout) {
  int t = blockIdx.x * blockDim.x + threadIdx.x;
  if (t >= N_B * 128) return;
  int b = t >> 7, u = t & 127;
  float gi = bih[u] + bhh[u];
  float gf = bih[128 + u] + bhh[128 + u];
  float gg = bih[256 + u] + bhh[256 + u];
  float go = bih[384 + u] + bhh[384 + u];
  const float* xr = x + (size_t)b * xdim;
  for (int k = 0; k < xdim; ++k) {
    float xv = xr[k];
    gi = fmaf(xv, Wih[(size_t)u * xdim + k], gi);
    gf = fmaf(xv, Wih[(size_t)(128 + u) * xdim + k], gf);
    gg = fmaf(xv, Wih[(size_t)(256 + u) * xdim + k], gg);
    go = fmaf(xv, Wih[(size_t)(384 + u) * xdim + k], go);
  }
  const float* hr = hin + (size_t)b * 128;
  for (int k = 0; k < 128; ++k) {
    float hv = hr[k];
    gi = fmaf(hv, Whh[(size_t)u * 128 + k], gi);
    gf = fmaf(hv, Whh[(size_t)(128 + u) * 128 + k], gf);
    gg = fmaf(hv, Whh[(size_t)(256 + u) * 128 + k], gg);
    go = fmaf(hv, Whh[(size_t)(384 + u) * 128 + k], go);
  }
  float c2 = sigm(gf) * cin[(size_t)b * 128 + u] + sigm(gi) * tanhf(gg);
  float h2 = sigm(go) * tanhf(c2);
  hout[(size_t)b * 128 + u] = h2;
  cout[(size_t)b * 128 + u] = c2;
}

// e[n] = dot(agg[n], q[gid[n]]); wave per node
__global__ void k_escore(const float* __restrict__ agg, const float* __restrict__ q,
                         const int* __restrict__ gid, float* __restrict__ e) {
  int wid = (blockIdx.x * blockDim.x + threadIdx.x) >> 6;
  int lane = threadIdx.x & 63;
  if (wid >= N_N) return;
  int g = gid[wid];
  float a = agg[(size_t)wid * 128 + lane] * q[g * 128 + lane] +
            agg[(size_t)wid * 128 + 64 + lane] * q[g * 128 + 64 + lane];
#pragma unroll
  for (int m = 1; m < 64; m <<= 1) a += __shfl_xor(a, m);
  if (lane == 0) e[wid] = a;
}

// per-graph softmax + readout + q_star write; block per graph, 128 threads
__global__ void k_pool(const float* __restrict__ agg, const float* __restrict__ e,
                       const int* __restrict__ gstart, const int* __restrict__ gend,
                       const float* __restrict__ h1, float* __restrict__ q_star) {
  int g = blockIdx.x;
  int s = gstart[g], t = gend[g];
  __shared__ float red[128];
  int tid = threadIdx.x;
  float m = -INFINITY;
  for (int n = s + tid; n < t; n += 128) m = fmaxf(m, e[n]);
  red[tid] = m;
  __syncthreads();
  for (int o = 64; o; o >>= 1) {
    if (tid < o) red[tid] = fmaxf(red[tid], red[tid + o]);
    __syncthreads();
  }
  m = red[0];
  __syncthreads();
  float sum = 0.f;
  for (int n = s + tid; n < t; n += 128) sum += expf(e[n] - m);
  red[tid] = sum;
  __syncthreads();
  for (int o = 64; o; o >>= 1) {
    if (tid < o) red[tid] += red[tid + o];
    __syncthreads();
  }
  float inv = (red[0] > 0.f) ? 1.f / red[0] : 0.f;
  float acc = 0.f;
  for (int n = s; n < t; ++n) acc += expf(e[n] - m) * inv * agg[(size_t)n * 128 + tid];
  q_star[(size_t)g * 256 + tid] = h1[(size_t)g * 128 + tid];
  q_star[(size_t)g * 256 + 128 + tid] = acc;
}

// out[b,d] = prelu(q_star[b] @ spW[:,d] + spb[d])
__global__ void k_out(const float* __restrict__ qs, const float* __restrict__ W,
                      const float* __restrict__ bias, const float* __restrict__ pa,
                      float* __restrict__ out) {
  int idx = blockIdx.x * blockDim.x + threadIdx.x;
  if (idx >= N_B * N_DH) return;
  int b = idx >> 12, d = idx & 4095;
  float acc = bias[d];
  const float* q = qs + (size_t)b * 256;
  for (int k = 0; k < 256; ++k) acc = fmaf(q[k], W[(size_t)k * 4096 + d], acc);
  float a = pa[0];
  out[idx] = acc >= 0.f ? acc : a * acc;
}

// ---------------- workspace layout (float offsets) ----------------
enum : size_t {
  OFF_X0 = 0,
  OFF_HA = OFF_X0 + (size_t)N_N * 64,
  OFF_HB = OFF_HA + (size_t)N_N * 64,
  OFF_EF = OFF_HB + (size_t)N_N * 64,
  OFF_EE = OFF_EF + (size_t)N_E * 16,
  OFF_HAE = OFF_EE + (size_t)N_A * 16,   // ha (angle-update activations per edge)
  OFF_AMSG = OFF_HAE + (size_t)N_E * 64,
  OFF_HBE = OFF_AMSG + (size_t)N_E * 64,
  OFF_NACC = OFF_HBE + (size_t)N_E * 64,
  OFF_AGG = OFF_NACC + (size_t)N_N * 64,
  OFF_E = OFF_AGG + (size_t)N_N * 128,
  OFF_WIHT = OFF_E + N_N,
  OFF_WHHT = OFF_WIHT + 192 * 64,
  OFF_QSTAR = OFF_WHHT + 192 * 64,   // zero block starts here
  OFF_H0A = OFF_QSTAR + N_B * 256,
  OFF_H0B = OFF_H0A + N_B * 128,
  OFF_C0A = OFF_H0B + N_B * 128,
  OFF_C0B = OFF_C0A + N_B * 128,
  OFF_H1A = OFF_C0B + N_B * 128,
  OFF_H1B = OFF_H1A + N_B * 128,
  OFF_C1A = OFF_H1B + N_B * 128,
  OFF_C1B = OFF_C1A + N_B * 128,
  OFF_GSTART = OFF_C1B + N_B * 128,
  OFF_GEND = OFF_GSTART + N_B,
  WS_FLOATS = OFF_GEND + N_B
};

extern "C" void kernel_launch(void* const* d_in, const int* in_sizes, int n_in,
                              void* d_out, int out_size, void* d_ws, size_t ws_size,
                              hipStream_t stream) {
  (void)in_sizes; (void)n_in; (void)out_size; (void)ws_size;
  const float* na    = (const float*)d_in[0];
  const float* ea    = (const float*)d_in[1];
  const float* el    = (const float*)d_in[2];
  const float* ang   = (const float*)d_in[3];
  const int*   esrc  = (const int*)d_in[4];
  const int*   edst  = (const int*)d_in[5];
  const int*   asrc  = (const int*)d_in[6];
  const int*   adst  = (const int*)d_in[7];
  const int*   gid   = (const int*)d_in[8];
  const float* projW = (const float*)d_in[9];
  const float* projb = (const float*)d_in[10];
  const float* bondW = (const float*)d_in[11];
  const float* bondb = (const float*)d_in[12];
  const float* efW   = (const float*)d_in[13];
  const float* efb   = (const float*)d_in[14];
  const float* gnnb  = (const float*)d_in[15];
  const float* buW   = (const float*)d_in[16];
  const float* bub   = (const float*)d_in[17];
  const float* auW   = (const float*)d_in[18];
  const float* aub   = (const float*)d_in[19];
  const float* gWih  = (const float*)d_in[20];
  const float* gWhh  = (const float*)d_in[21];
  const float* gbih  = (const float*)d_in[22];
  const float* gbhh  = (const float*)d_in[23];
  const float* sWih0 = (const float*)d_in[24];
  const float* sWhh0 = (const float*)d_in[25];
  const float* sbih0 = (const float*)d_in[26];
  const float* sbhh0 = (const float*)d_in[27];
  const float* sWih1 = (const float*)d_in[28];
  const float* sWhh1 = (const float*)d_in[29];
  const float* sbih1 = (const float*)d_in[30];
  const float* sbhh1 = (const float*)d_in[31];
  const float* spW   = (const float*)d_in[32];
  const float* spb   = (const float*)d_in[33];
  const float* pa    = (const float*)d_in[34];
  float* out = (float*)d_out;
  float* ws = (float*)d_ws;

  float* x0   = ws + OFF_X0;
  float* hA   = ws + OFF_HA;
  float* hB   = ws + OFF_HB;
  float* ef   = ws + OFF_EF;
  float* ee   = ws + OFF_EE;
  float* ha   = ws + OFF_HAE;
  float* amsg = ws + OFF_AMSG;
  float* hb   = ws + OFF_HBE;
  float* nacc = ws + OFF_NACC;
  float* agg  = ws + OFF_AGG;
  float* ev   = ws + OFF_E;
  float* wihT = ws + OFF_WIHT;
  float* whhT = ws + OFF_WHHT;
  float* qstar = ws + OFF_QSTAR;
  float* h0a = ws + OFF_H0A; float* h0b = ws + OFF_H0B;
  float* c0a = ws + OFF_C0A; float* c0b = ws + OFF_C0B;
  float* h1a = ws + OFF_H1A; float* h1b = ws + OFF_H1B;
  float* c1a = ws + OFF_C1A; float* c1b = ws + OFF_C1B;
  int* gstart = (int*)(ws + OFF_GSTART);
  int* gend   = (int*)(ws + OFF_GEND);

  // ---- setup ----
  k_proj<<<(N_N * 64 + 255) / 256, 256, 0, stream>>>(na, projW, projb, x0);
  k_edgefeat<<<(N_E + 255) / 256, 256, 0, stream>>>(ea, el, ef);
  k_anglefeat<<<(N_A + 255) / 256, 256, 0, stream>>>(ang, el, asrc, ee);
  k_transpose<<<(192 * 64 + 255) / 256, 256, 0, stream>>>(gWih, wihT, 192, 64);
  k_transpose<<<(192 * 64 + 255) / 256, 256, 0, stream>>>(gWhh, whhT, 192, 64);
  hipMemsetAsync(gstart, 0x7f, N_B * sizeof(int), stream);
  hipMemsetAsync(gend, 0, N_B * sizeof(int), stream);
  k_bounds<<<(N_N + 255) / 256, 256, 0, stream>>>(gid, gstart, gend);

  // ---- message-passing steps ----
  const float* cur = x0;
  float* bufs[2] = {hA, hB};
  for (int s = 0; s < 4; ++s) {
    k_edge_mlp<false><<<(N_E * 64 + 255) / 256, 256, 0, stream>>>(cur, esrc, auW, aub,
                                                                  nullptr, ha);
    hipMemsetAsync(amsg, 0, (size_t)N_E * 64 * sizeof(float), stream);
    k_item_mm<true><<<dim3((N_A + 255) / 256, 4), 256, 0, stream>>>(
        ha, asrc, ee, efW, efb, adst, amsg, N_A);
    k_edge_mlp<true><<<(N_E * 64 + 255) / 256, 256, 0, stream>>>(cur, esrc, buW, bub,
                                                                 amsg, hb);
    hipMemsetAsync(nacc, 0, (size_t)N_N * 64 * sizeof(float), stream);
    k_item_mm<false><<<dim3((N_E + 255) / 256, 4), 256, 0, stream>>>(
        hb, nullptr, ef, bondW, bondb, edst, nacc, N_E);
    float* nxt = bufs[s & 1];
    k_gru<<<(N_N * 64 + 255) / 256, 256, 0, stream>>>(nacc, gnnb, cur, wihT, whhT,
                                                      gbih, gbhh, nxt);
    cur = nxt;
  }
  k_agg<<<(N_N * 64 + 255) / 256, 256, 0, stream>>>(cur, x0, agg);

  // ---- Set2Set ----
  hipMemsetAsync(qstar, 0, (size_t)(N_B * 256 + 8 * N_B * 128) * sizeof(float), stream);
  float *h0i = h0a, *h0o = h0b, *c0i = c0a, *c0o = c0b;
  float *h1i = h1a, *h1o = h1b, *c1i = c1a, *c1o = c1b;
  for (int it = 0; it < 3; ++it) {
    k_lstm<<<(N_B * 128 + 255) / 256, 256, 0, stream>>>(qstar, 256, h0i, c0i, sWih0,
                                                        sWhh0, sbih0, sbhh0, h0o, c0o);
    k_lstm<<<(N_B * 128 + 255) / 256, 256, 0, stream>>>(h0o, 128, h1i, c1i, sWih1,
                                                        sWhh1, sbih1, sbhh1, h1o, c1o);
    k_escore<<<(N_N * 64 + 255) / 256, 256, 0, stream>>>(agg, h1o, gid, ev);
    k_pool<<<N_B, 128, 0, stream>>>(agg, ev, gstart, gend, h1o, qstar);
    float* tmp;
    tmp = h0i; h0i = h0o; h0o = tmp;
    tmp = c0i; c0i = c0o; c0o = tmp;
    tmp = h1i; h1i = h1o; h1o = tmp;
    tmp = c1i; c1i = c1o; c1o = tmp;
  }
  k_out<<<(N_B * N_DH + 255) / 256, 256, 0, stream>>>(qstar, spW, spb, pa, out);
}

// Round 2
// 1262.878 us; speedup vs baseline: 2.1472x; 2.1472x over previous
//
#include <hip/hip_runtime.h>
#include <math.h>

#define N_N 8000
#define N_E 12000
#define N_A 48000
#define N_B 64
#define N_H 64
#define N_DH 4096

typedef _Float16 h16;
typedef __attribute__((ext_vector_type(8))) _Float16 h16x8;
typedef __attribute__((ext_vector_type(4))) float f32x4;

__device__ __forceinline__ float atomAddF(float* p, float v) {
  return __hip_atomic_fetch_add(p, v, __ATOMIC_RELAXED, __HIP_MEMORY_SCOPE_AGENT);
}
__device__ __forceinline__ float sigm(float x) { return 1.f / (1.f + expf(-x)); }

// ---------------- setup kernels ----------------

// x0 = relu(node_attribute @ projW + projb); wave per node, lane = out-dim
__global__ void k_proj(const float* __restrict__ na, const float* __restrict__ W,
                       const float* __restrict__ b, float* __restrict__ x0) {
  int wid = (blockIdx.x * blockDim.x + threadIdx.x) >> 6;
  int lane = threadIdx.x & 63;
  if (wid >= N_N) return;
  const float* row = na + (size_t)wid * 110;
  float acc = b[lane];
  for (int k = 0; k < 110; ++k) acc = fmaf(row[k], W[k * 64 + lane], acc);
  x0[(size_t)wid * 64 + lane] = fmaxf(acc, 0.f);
}

// edge_feat[e] = [edge_attribute(8) | rbf(edge_length, K=8, cutoff=4)]
__global__ void k_edgefeat(const float* __restrict__ ea, const float* __restrict__ el,
                           float* __restrict__ ef) {
  int e = blockIdx.x * blockDim.x + threadIdx.x;
  if (e >= N_E) return;
  float x = el[e];
  const float g2 = (7.f / 4.f) * (7.f / 4.f);
#pragma unroll
  for (int j = 0; j < 8; ++j) ef[e * 16 + j] = ea[e * 8 + j];
#pragma unroll
  for (int j = 0; j < 8; ++j) {
    float d = x - j * (4.f / 7.f);
    ef[e * 16 + 8 + j] = expf(-g2 * d * d);
  }
}

// ee_feat[a] = [rbf(angle, 8, pi) | rbf(edge_length[angle_src], 8, 4)]
__global__ void k_anglefeat(const float* __restrict__ ang, const float* __restrict__ el,
                            const int* __restrict__ asrc, float* __restrict__ ee) {
  int a = blockIdx.x * blockDim.x + threadIdx.x;
  if (a >= N_A) return;
  const float PIf = 3.14159265358979323846f;
  float x = ang[a];
  float g1 = (7.f / PIf) * (7.f / PIf);
#pragma unroll
  for (int j = 0; j < 8; ++j) {
    float d = x - j * (PIf / 7.f);
    ee[a * 16 + j] = expf(-g1 * d * d);
  }
  float y = el[asrc[a]];
  float g2 = (7.f / 4.f) * (7.f / 4.f);
#pragma unroll
  for (int j = 0; j < 8; ++j) {
    float d = y - j * (4.f / 7.f);
    ee[a * 16 + 8 + j] = expf(-g2 * d * d);
  }
}

// W[R][C] -> WT[C][R] (f32, for GRU)
__global__ void k_transpose(const float* __restrict__ W, float* __restrict__ WT,
                            int R, int C) {
  int idx = blockIdx.x * blockDim.x + threadIdx.x;
  if (idx >= R * C) return;
  int r = idx / C, c = idx % C;
  WT[c * R + r] = W[idx];
}

// Tt[n=k*64+o][i] = (k<16 ? W[k*4096 + i*64 + o] : b2[i*64+o]), fp16. n in [0,1088)
__global__ void k_maket(const float* __restrict__ W, const float* __restrict__ b2,
                        h16* __restrict__ Tt) {
  int idx = blockIdx.x * blockDim.x + threadIdx.x;
  if (idx >= 1088 * 64) return;
  int n = idx >> 6, i = idx & 63;
  int k = n >> 6, o = n & 63;
  float val = (k < 16) ? W[(size_t)k * 4096 + i * 64 + o] : b2[i * 64 + o];
  Tt[(size_t)n * 64 + i] = (h16)val;
}

// Wt[o*64+i] = W[i*64+o], fp16 (B^T layout for the 64x64 MLP GEMMs)
__global__ void k_prep_wt(const float* __restrict__ W, h16* __restrict__ Wt) {
  int idx = blockIdx.x * blockDim.x + threadIdx.x;
  if (idx >= 4096) return;
  int o = idx >> 6, i = idx & 63;
  Wt[o * 64 + i] = (h16)W[i * 64 + o];
}

__global__ void k_bounds(const int* __restrict__ gid, int* __restrict__ gstart,
                         int* __restrict__ gend) {
  int n = blockIdx.x * blockDim.x + threadIdx.x;
  if (n >= N_N) return;
  int g = gid[n];
  atomicMin(&gstart[g], n);
  atomicMax(&gend[g], n + 1);
}

// ---------------- MFMA step kernels ----------------
// Fragment maps (16x16x32 f16, verified family):
//   A[m,k]: m = lane&15, k = ks*32 + 8*(lane>>4) + j (j=0..7 contiguous)
//   B[n,k]: n = lane&15, same k map (B^T storage [N][K])
//   D[m,n]: n = lane&15, m = (lane>>4)*4 + reg

// out[e,:] = relu(v[src[e]] @ W + b) (+ amsg[e,:]) -> fp16. Wave = 32 edges.
template <bool ADD_AMSG>
__global__ __launch_bounds__(256) void k_mfma_mlp(
    const float* __restrict__ v, const int* __restrict__ src,
    const h16* __restrict__ Wt, const float* __restrict__ bias,
    const float* __restrict__ amsg, h16* __restrict__ out, int T) {
  int tid = threadIdx.x, wave = tid >> 6, lane = tid & 63;
  int l15 = lane & 15, lq = lane >> 4;
  int ib0 = blockIdx.x * 128 + wave * 32;

  h16x8 afr[2][2];
#pragma unroll
  for (int s = 0; s < 2; ++s) {
    int item = ib0 + s * 16 + l15;
    if (item >= T) item = T - 1;
    const float* vp = v + (size_t)src[item] * 64;
#pragma unroll
    for (int ks = 0; ks < 2; ++ks) {
      const float4* p = (const float4*)(vp + ks * 32 + 8 * lq);
      float4 x0 = p[0], x1 = p[1];
      h16x8 a;
      a[0] = (h16)x0.x; a[1] = (h16)x0.y; a[2] = (h16)x0.z; a[3] = (h16)x0.w;
      a[4] = (h16)x1.x; a[5] = (h16)x1.y; a[6] = (h16)x1.z; a[7] = (h16)x1.w;
      afr[s][ks] = a;
    }
  }
  h16x8 bfr[4][2];
#pragma unroll
  for (int nt = 0; nt < 4; ++nt)
#pragma unroll
    for (int ks = 0; ks < 2; ++ks)
      bfr[nt][ks] = *(const h16x8*)(Wt + (size_t)(nt * 16 + l15) * 64 + ks * 32 + 8 * lq);

  f32x4 acc[2][4];
#pragma unroll
  for (int s = 0; s < 2; ++s)
#pragma unroll
    for (int nt = 0; nt < 4; ++nt) acc[s][nt] = (f32x4){0.f, 0.f, 0.f, 0.f};
#pragma unroll
  for (int s = 0; s < 2; ++s)
#pragma unroll
    for (int nt = 0; nt < 4; ++nt)
#pragma unroll
      for (int ks = 0; ks < 2; ++ks)
        acc[s][nt] = __builtin_amdgcn_mfma_f32_16x16x32_f16(afr[s][ks], bfr[nt][ks],
                                                            acc[s][nt], 0, 0, 0);
#pragma unroll
  for (int s = 0; s < 2; ++s) {
#pragma unroll
    for (int nt = 0; nt < 4; ++nt) {
      int o = nt * 16 + l15;
      float bo = bias[o];
#pragma unroll
      for (int r = 0; r < 4; ++r) {
        int item = ib0 + s * 16 + lq * 4 + r;
        if (item < T) {
          float val = fmaxf(acc[s][nt][r] + bo, 0.f);
          if (ADD_AMSG) val += amsg[(size_t)item * 64 + o];
          out[(size_t)item * 64 + o] = (h16)val;
        }
      }
    }
  }
}

// m[a,o] = sum_{kk<17} featx[a,kk] * (v[a,:] @ Tt[kk*64+o,:]); atomic scatter to dst.
// Wave = 32 items; feat folded into A-operand per kk (featx[:,16] = 1 handled by peel).
template <bool GATHER>
__global__ __launch_bounds__(256) void k_mfma_mm(
    const h16* __restrict__ v, const int* __restrict__ src,
    const float* __restrict__ feat, const h16* __restrict__ Tt,
    const int* __restrict__ dst, float* __restrict__ out, int T) {
  __shared__ float f_lds[128 * 17];
  __shared__ int dst_lds[128];
  int tid = threadIdx.x;
  int base = blockIdx.x * 128;
  for (int e = tid; e < 128 * 16; e += 256) {
    int il = e >> 4, k = e & 15;
    int g = base + il;
    if (g >= T) g = T - 1;
    f_lds[il * 17 + k] = feat[(size_t)g * 16 + k];
  }
  if (tid < 128) {
    int g = base + tid;
    if (g >= T) g = T - 1;
    dst_lds[tid] = dst[g];
  }
  __syncthreads();

  int wave = tid >> 6, lane = tid & 63;
  int l15 = lane & 15, lq = lane >> 4;
  int ibl = wave * 32;
  int ib0 = base + ibl;

  h16x8 afr[2][2];
#pragma unroll
  for (int s = 0; s < 2; ++s) {
    int item = ib0 + s * 16 + l15;
    if (item >= T) item = T - 1;
    int vi = GATHER ? src[item] : item;
    const h16* vp = v + (size_t)vi * 64;
#pragma unroll
    for (int ks = 0; ks < 2; ++ks)
      afr[s][ks] = *(const h16x8*)(vp + ks * 32 + 8 * lq);
  }

  f32x4 acc[2][4];
#pragma unroll
  for (int s = 0; s < 2; ++s)
#pragma unroll
    for (int nt = 0; nt < 4; ++nt) acc[s][nt] = (f32x4){0.f, 0.f, 0.f, 0.f};

  for (int kk = 0; kk < 16; ++kk) {
    h16x8 bfr[4][2];
#pragma unroll
    for (int nt = 0; nt < 4; ++nt)
#pragma unroll
      for (int ks = 0; ks < 2; ++ks)
        bfr[nt][ks] = *(const h16x8*)(Tt + (size_t)(kk * 64 + nt * 16 + l15) * 64 +
                                      ks * 32 + 8 * lq);
    h16x8 a2[2][2];
#pragma unroll
    for (int s = 0; s < 2; ++s) {
      h16 fs = (h16)f_lds[(ibl + s * 16 + l15) * 17 + kk];
      a2[s][0] = afr[s][0] * fs;
      a2[s][1] = afr[s][1] * fs;
    }
#pragma unroll
    for (int s = 0; s < 2; ++s)
#pragma unroll
      for (int nt = 0; nt < 4; ++nt)
#pragma unroll
        for (int ks = 0; ks < 2; ++ks)
          acc[s][nt] = __builtin_amdgcn_mfma_f32_16x16x32_f16(a2[s][ks], bfr[nt][ks],
                                                              acc[s][nt], 0, 0, 0);
  }
  // bias row (kk=16, featx=1): use raw A frags
  {
    h16x8 bfr[4][2];
#pragma unroll
    for (int nt = 0; nt < 4; ++nt)
#pragma unroll
      for (int ks = 0; ks < 2; ++ks)
        bfr[nt][ks] = *(const h16x8*)(Tt + (size_t)(16 * 64 + nt * 16 + l15) * 64 +
                                      ks * 32 + 8 * lq);
#pragma unroll
    for (int s = 0; s < 2; ++s)
#pragma unroll
      for (int nt = 0; nt < 4; ++nt)
#pragma unroll
        for (int ks = 0; ks < 2; ++ks)
          acc[s][nt] = __builtin_amdgcn_mfma_f32_16x16x32_f16(afr[s][ks], bfr[nt][ks],
                                                              acc[s][nt], 0, 0, 0);
  }

#pragma unroll
  for (int s = 0; s < 2; ++s) {
#pragma unroll
    for (int r = 0; r < 4; ++r) {
      int il = ibl + s * 16 + lq * 4 + r;
      int item = base + il;
      if (item < T) {
        float* op = out + (size_t)dst_lds[il] * 64;
#pragma unroll
        for (int nt = 0; nt < 4; ++nt)
          atomAddF(op + nt * 16 + l15, acc[s][nt][r]);
      }
    }
  }
}

// fused: x = relu(nacc + gnn_b); h' = GRU(x, h). wave per node, lane = unit
__global__ void k_gru(const float* __restrict__ nacc, const float* __restrict__ gnnb,
                      const float* __restrict__ h, const float* __restrict__ WihT,
                      const float* __restrict__ WhhT, const float* __restrict__ bih,
                      const float* __restrict__ bhh, float* __restrict__ hout) {
  int wid = (blockIdx.x * blockDim.x + threadIdx.x) >> 6;
  int lane = threadIdx.x & 63;
  if (wid >= N_N) return;
  const float* xr = nacc + (size_t)wid * 64;
  const float* hr = h + (size_t)wid * 64;
  float air = bih[lane], aiz = bih[64 + lane], ain = bih[128 + lane];
  float ahr = bhh[lane], ahz = bhh[64 + lane], ahn = bhh[128 + lane];
#pragma unroll 8
  for (int i = 0; i < 64; ++i) {
    float xi = fmaxf(xr[i] + gnnb[i], 0.f);
    float hi = hr[i];
    air = fmaf(xi, WihT[i * 192 + lane], air);
    aiz = fmaf(xi, WihT[i * 192 + 64 + lane], aiz);
    ain = fmaf(xi, WihT[i * 192 + 128 + lane], ain);
    ahr = fmaf(hi, WhhT[i * 192 + lane], ahr);
    ahz = fmaf(hi, WhhT[i * 192 + 64 + lane], ahz);
    ahn = fmaf(hi, WhhT[i * 192 + 128 + lane], ahn);
  }
  float r = sigm(air + ahr);
  float z = sigm(aiz + ahz);
  float n = tanhf(ain + r * ahn);
  hout[(size_t)wid * 64 + lane] = (1.f - z) * n + z * hr[lane];
}

__global__ void k_agg(const float* __restrict__ h, const float* __restrict__ x0,
                      float* __restrict__ agg) {
  int idx = blockIdx.x * blockDim.x + threadIdx.x;
  if (idx >= N_N * 64) return;
  int n = idx >> 6, d = idx & 63;
  agg[(size_t)n * 128 + d] = h[idx];
  agg[(size_t)n * 128 + 64 + d] = x0[idx];
}

// ---------------- Set2Set ----------------

__global__ void k_lstm(const float* __restrict__ x, int xdim,
                       const float* __restrict__ hin, const float* __restrict__ cin,
                       const float* __restrict__ Wih, const float* __restrict__ Whh,
                       const float* __restrict__ bih, const float* __restrict__ bhh,
                       float* __restrict__ hout, float* __restrict__ cout) {
  int t = blockIdx.x * blockDim.x + threadIdx.x;
  if (t >= N_B * 128) return;
  int b = t >> 7, u = t & 127;
  float gi = bih[u] + bhh[u];
  float gf = bih[128 + u] + bhh[128 + u];
  float gg = bih[256 + u] + bhh[256 + u];
  float go = bih[384 + u] + bhh[384 + u];
  const float* xr = x + (size_t)b * xdim;
  for (int k = 0; k < xdim; ++k) {
    float xv = xr[k];
    gi = fmaf(xv, Wih[(size_t)u * xdim + k], gi);
    gf = fmaf(xv, Wih[(size_t)(128 + u) * xdim + k], gf);
    gg = fmaf(xv, Wih[(size_t)(256 + u) * xdim + k], gg);
    go = fmaf(xv, Wih[(size_t)(384 + u) * xdim + k], go);
  }
  const float* hr = hin + (size_t)b * 128;
  for (int k = 0; k < 128; ++k) {
    float hv = hr[k];
    gi = fmaf(hv, Whh[(size_t)u * 128 + k], gi);
    gf = fmaf(hv, Whh[(size_t)(128 + u) * 128 + k], gf);
    gg = fmaf(hv, Whh[(size_t)(256 + u) * 128 + k], gg);
    go = fmaf(hv, Whh[(size_t)(384 + u) * 128 + k], go);
  }
  float c2 = sigm(gf) * cin[(size_t)b * 128 + u] + sigm(gi) * tanhf(gg);
  float h2 = sigm(go) * tanhf(c2);
  hout[(size_t)b * 128 + u] = h2;
  cout[(size_t)b * 128 + u] = c2;
}

__global__ void k_escore(const float* __restrict__ agg, const float* __restrict__ q,
                         const int* __restrict__ gid, float* __restrict__ e) {
  int wid = (blockIdx.x * blockDim.x + threadIdx.x) >> 6;
  int lane = threadIdx.x & 63;
  if (wid >= N_N) return;
  int g = gid[wid];
  float a = agg[(size_t)wid * 128 + lane] * q[g * 128 + lane] +
            agg[(size_t)wid * 128 + 64 + lane] * q[g * 128 + 64 + lane];
#pragma unroll
  for (int m = 1; m < 64; m <<= 1) a += __shfl_xor(a, m);
  if (lane == 0) e[wid] = a;
}

__global__ void k_pool(const float* __restrict__ agg, const float* __restrict__ e,
                       const int* __restrict__ gstart, const int* __restrict__ gend,
                       const float* __restrict__ h1, float* __restrict__ q_star) {
  int g = blockIdx.x;
  int s = gstart[g], t = gend[g];
  __shared__ float red[128];
  int tid = threadIdx.x;
  float m = -INFINITY;
  for (int n = s + tid; n < t; n += 128) m = fmaxf(m, e[n]);
  red[tid] = m;
  __syncthreads();
  for (int o = 64; o; o >>= 1) {
    if (tid < o) red[tid] = fmaxf(red[tid], red[tid + o]);
    __syncthreads();
  }
  m = red[0];
  __syncthreads();
  float sum = 0.f;
  for (int n = s + tid; n < t; n += 128) sum += expf(e[n] - m);
  red[tid] = sum;
  __syncthreads();
  for (int o = 64; o; o >>= 1) {
    if (tid < o) red[tid] += red[tid + o];
    __syncthreads();
  }
  float inv = (red[0] > 0.f) ? 1.f / red[0] : 0.f;
  float acc = 0.f;
  for (int n = s; n < t; ++n) acc += expf(e[n] - m) * inv * agg[(size_t)n * 128 + tid];
  q_star[(size_t)g * 256 + tid] = h1[(size_t)g * 128 + tid];
  q_star[(size_t)g * 256 + 128 + tid] = acc;
}

__global__ void k_out(const float* __restrict__ qs, const float* __restrict__ W,
                      const float* __restrict__ bias, const float* __restrict__ pa,
                      float* __restrict__ out) {
  int idx = blockIdx.x * blockDim.x + threadIdx.x;
  if (idx >= N_B * N_DH) return;
  int b = idx >> 12, d = idx & 4095;
  float acc = bias[d];
  const float* q = qs + (size_t)b * 256;
  for (int k = 0; k < 256; ++k) acc = fmaf(q[k], W[(size_t)k * 4096 + d], acc);
  float a = pa[0];
  out[idx] = acc >= 0.f ? acc : a * acc;
}

// ---------------- workspace layout (float offsets) ----------------
enum : size_t {
  OFF_X0 = 0,
  OFF_HA = OFF_X0 + (size_t)N_N * 64,
  OFF_HB = OFF_HA + (size_t)N_N * 64,
  OFF_EF = OFF_HB + (size_t)N_N * 64,
  OFF_EE = OFF_EF + (size_t)N_E * 16,
  OFF_HAE = OFF_EE + (size_t)N_A * 16,   // ha_h fp16 (uses half the slot)
  OFF_AMSG = OFF_HAE + (size_t)N_E * 64,
  OFF_HBE = OFF_AMSG + (size_t)N_E * 64, // hb_h fp16
  OFF_NACC = OFF_HBE + (size_t)N_E * 64,
  OFF_AGG = OFF_NACC + (size_t)N_N * 64,
  OFF_E = OFF_AGG + (size_t)N_N * 128,
  OFF_WIHT = OFF_E + N_N,
  OFF_WHHT = OFF_WIHT + 192 * 64,
  OFF_QSTAR = OFF_WHHT + 192 * 64,
  OFF_H0A = OFF_QSTAR + N_B * 256,
  OFF_H0B = OFF_H0A + N_B * 128,
  OFF_C0A = OFF_H0B + N_B * 128,
  OFF_C0B = OFF_C0A + N_B * 128,
  OFF_H1A = OFF_C0B + N_B * 128,
  OFF_H1B = OFF_H1A + N_B * 128,
  OFF_C1A = OFF_H1B + N_B * 128,
  OFF_C1B = OFF_C1A + N_B * 128,
  OFF_GSTART = OFF_C1B + N_B * 128,
  OFF_GEND = OFF_GSTART + N_B,
  OFF_TT_ANG = (OFF_GEND + N_B + 63) & ~(size_t)63,  // 1088*64 fp16 = 34816 floats
  OFF_TT_BOND = OFF_TT_ANG + 34816,
  OFF_WT_AU = OFF_TT_BOND + 34816,       // 4096 fp16 = 2048 floats
  OFF_WT_BU = OFF_WT_AU + 2048,
  WS_FLOATS = OFF_WT_BU + 2048
};

extern "C" void kernel_launch(void* const* d_in, const int* in_sizes, int n_in,
                              void* d_out, int out_size, void* d_ws, size_t ws_size,
                              hipStream_t stream) {
  (void)in_sizes; (void)n_in; (void)out_size; (void)ws_size;
  const float* na    = (const float*)d_in[0];
  const float* ea    = (const float*)d_in[1];
  const float* el    = (const float*)d_in[2];
  const float* ang   = (const float*)d_in[3];
  const int*   esrc  = (const int*)d_in[4];
  const int*   edst  = (const int*)d_in[5];
  const int*   asrc  = (const int*)d_in[6];
  const int*   adst  = (const int*)d_in[7];
  const int*   gid   = (const int*)d_in[8];
  const float* projW = (const float*)d_in[9];
  const float* projb = (const float*)d_in[10];
  const float* bondW = (const float*)d_in[11];
  const float* bondb = (const float*)d_in[12];
  const float* efW   = (const float*)d_in[13];
  const float* efb   = (const float*)d_in[14];
  const float* gnnb  = (const float*)d_in[15];
  const float* buW   = (const float*)d_in[16];
  const float* bub   = (const float*)d_in[17];
  const float* auW   = (const float*)d_in[18];
  const float* aub   = (const float*)d_in[19];
  const float* gWih  = (const float*)d_in[20];
  const float* gWhh  = (const float*)d_in[21];
  const float* gbih  = (const float*)d_in[22];
  const float* gbhh  = (const float*)d_in[23];
  const float* sWih0 = (const float*)d_in[24];
  const float* sWhh0 = (const float*)d_in[25];
  const float* sbih0 = (const float*)d_in[26];
  const float* sbhh0 = (const float*)d_in[27];
  const float* sWih1 = (const float*)d_in[28];
  const float* sWhh1 = (const float*)d_in[29];
  const float* sbih1 = (const float*)d_in[30];
  const float* sbhh1 = (const float*)d_in[31];
  const float* spW   = (const float*)d_in[32];
  const float* spb   = (const float*)d_in[33];
  const float* pa    = (const float*)d_in[34];
  float* out = (float*)d_out;
  float* ws = (float*)d_ws;

  float* x0   = ws + OFF_X0;
  float* hA   = ws + OFF_HA;
  float* hB   = ws + OFF_HB;
  float* ef   = ws + OFF_EF;
  float* ee   = ws + OFF_EE;
  h16*   ha_h = (h16*)(ws + OFF_HAE);
  float* amsg = ws + OFF_AMSG;
  h16*   hb_h = (h16*)(ws + OFF_HBE);
  float* nacc = ws + OFF_NACC;
  float* agg  = ws + OFF_AGG;
  float* ev   = ws + OFF_E;
  float* wihT = ws + OFF_WIHT;
  float* whhT = ws + OFF_WHHT;
  float* qstar = ws + OFF_QSTAR;
  float* h0a = ws + OFF_H0A; float* h0b = ws + OFF_H0B;
  float* c0a = ws + OFF_C0A; float* c0b = ws + OFF_C0B;
  float* h1a = ws + OFF_H1A; float* h1b = ws + OFF_H1B;
  float* c1a = ws + OFF_C1A; float* c1b = ws + OFF_C1B;
  int* gstart = (int*)(ws + OFF_GSTART);
  int* gend   = (int*)(ws + OFF_GEND);
  h16* ttA = (h16*)(ws + OFF_TT_ANG);
  h16* ttB = (h16*)(ws + OFF_TT_BOND);
  h16* wtAU = (h16*)(ws + OFF_WT_AU);
  h16* wtBU = (h16*)(ws + OFF_WT_BU);

  // ---- setup ----
  k_proj<<<(N_N * 64 + 255) / 256, 256, 0, stream>>>(na, projW, projb, x0);
  k_edgefeat<<<(N_E + 255) / 256, 256, 0, stream>>>(ea, el, ef);
  k_anglefeat<<<(N_A + 255) / 256, 256, 0, stream>>>(ang, el, asrc, ee);
  k_transpose<<<(192 * 64 + 255) / 256, 256, 0, stream>>>(gWih, wihT, 192, 64);
  k_transpose<<<(192 * 64 + 255) / 256, 256, 0, stream>>>(gWhh, whhT, 192, 64);
  k_maket<<<(1088 * 64 + 255) / 256, 256, 0, stream>>>(efW, efb, ttA);
  k_maket<<<(1088 * 64 + 255) / 256, 256, 0, stream>>>(bondW, bondb, ttB);
  k_prep_wt<<<16, 256, 0, stream>>>(auW, wtAU);
  k_prep_wt<<<16, 256, 0, stream>>>(buW, wtBU);
  hipMemsetAsync(gstart, 0x7f, N_B * sizeof(int), stream);
  hipMemsetAsync(gend, 0, N_B * sizeof(int), stream);
  k_bounds<<<(N_N + 255) / 256, 256, 0, stream>>>(gid, gstart, gend);

  // ---- message-passing steps ----
  const float* cur = x0;
  float* bufs[2] = {hA, hB};
  for (int s = 0; s < 4; ++s) {
    k_mfma_mlp<false><<<(N_E + 127) / 128, 256, 0, stream>>>(cur, esrc, wtAU, aub,
                                                             nullptr, ha_h, N_E);
    hipMemsetAsync(amsg, 0, (size_t)N_E * 64 * sizeof(float), stream);
    k_mfma_mm<true><<<(N_A + 127) / 128, 256, 0, stream>>>(ha_h, asrc, ee, ttA, adst,
                                                           amsg, N_A);
    k_mfma_mlp<true><<<(N_E + 127) / 128, 256, 0, stream>>>(cur, esrc, wtBU, bub,
                                                            amsg, hb_h, N_E);
    hipMemsetAsync(nacc, 0, (size_t)N_N * 64 * sizeof(float), stream);
    k_mfma_mm<false><<<(N_E + 127) / 128, 256, 0, stream>>>(hb_h, nullptr, ef, ttB,
                                                            edst, nacc, N_E);
    float* nxt = bufs[s & 1];
    k_gru<<<(N_N * 64 + 255) / 256, 256, 0, stream>>>(nacc, gnnb, cur, wihT, whhT,
                                                      gbih, gbhh, nxt);
    cur = nxt;
  }
  k_agg<<<(N_N * 64 + 255) / 256, 256, 0, stream>>>(cur, x0, agg);

  // ---- Set2Set ----
  hipMemsetAsync(qstar, 0, (size_t)(N_B * 256 + 8 * N_B * 128) * sizeof(float), stream);
  float *h0i = h0a, *h0o = h0b, *c0i = c0a, *c0o = c0b;
  float *h1i = h1a, *h1o = h1b, *c1i = c1a, *c1o = c1b;
  for (int it = 0; it < 3; ++it) {
    k_lstm<<<(N_B * 128 + 255) / 256, 256, 0, stream>>>(qstar, 256, h0i, c0i, sWih0,
                                                        sWhh0, sbih0, sbhh0, h0o, c0o);
    k_lstm<<<(N_B * 128 + 255) / 256, 256, 0, stream>>>(h0o, 128, h1i, c1i, sWih1,
                                                        sWhh1, sbih1, sbhh1, h1o, c1o);
    k_escore<<<(N_N * 64 + 255) / 256, 256, 0, stream>>>(agg, h1o, gid, ev);
    k_pool<<<N_B, 128, 0, stream>>>(agg, ev, gstart, gend, h1o, qstar);
    float* tmp;
    tmp = h0i; h0i = h0o; h0o = tmp;
    tmp = c0i; c0i = c0o; c0o = tmp;
    tmp = h1i; h1i = h1o; h1o = tmp;
    tmp = c1i; c1i = c1o; c1o = tmp;
  }
  k_out<<<(N_B * N_DH + 255) / 256, 256, 0, stream>>>(qstar, spW, spb, pa, out);
}

// Round 3
// 681.464 us; speedup vs baseline: 3.9791x; 1.8532x over previous
//
#include <hip/hip_runtime.h>
#include <math.h>

#define N_N 8000
#define N_E 12000
#define N_A 48000
#define N_B 64
#define N_H 64
#define N_DH 4096

typedef _Float16 h16;
typedef __attribute__((ext_vector_type(8))) _Float16 h16x8;
typedef __attribute__((ext_vector_type(4))) float f32x4;

__device__ __forceinline__ float atomAddF(float* p, float v) {
  return __hip_atomic_fetch_add(p, v, __ATOMIC_RELAXED, __HIP_MEMORY_SCOPE_AGENT);
}
__device__ __forceinline__ float sigm(float x) { return 1.f / (1.f + expf(-x)); }

// ---------------- setup kernels ----------------

// x0 = relu(node_attribute @ projW + projb); wave per node, lane = out-dim
__global__ void k_proj(const float* __restrict__ na, const float* __restrict__ W,
                       const float* __restrict__ b, float* __restrict__ x0) {
  int wid = (blockIdx.x * blockDim.x + threadIdx.x) >> 6;
  int lane = threadIdx.x & 63;
  if (wid >= N_N) return;
  const float* row = na + (size_t)wid * 110;
  float acc = b[lane];
  for (int k = 0; k < 110; ++k) acc = fmaf(row[k], W[k * 64 + lane], acc);
  x0[(size_t)wid * 64 + lane] = fmaxf(acc, 0.f);
}

// edge_feat[e] = [edge_attribute(8) | rbf(edge_length, K=8, cutoff=4)]
__global__ void k_edgefeat(const float* __restrict__ ea, const float* __restrict__ el,
                           float* __restrict__ ef) {
  int e = blockIdx.x * blockDim.x + threadIdx.x;
  if (e >= N_E) return;
  float x = el[e];
  const float g2 = (7.f / 4.f) * (7.f / 4.f);
#pragma unroll
  for (int j = 0; j < 8; ++j) ef[e * 16 + j] = ea[e * 8 + j];
#pragma unroll
  for (int j = 0; j < 8; ++j) {
    float d = x - j * (4.f / 7.f);
    ef[e * 16 + 8 + j] = expf(-g2 * d * d);
  }
}

// ee_feat[a] = [rbf(angle, 8, pi) | rbf(edge_length[angle_src], 8, 4)]
__global__ void k_anglefeat(const float* __restrict__ ang, const float* __restrict__ el,
                            const int* __restrict__ asrc, float* __restrict__ ee) {
  int a = blockIdx.x * blockDim.x + threadIdx.x;
  if (a >= N_A) return;
  const float PIf = 3.14159265358979323846f;
  float x = ang[a];
  float g1 = (7.f / PIf) * (7.f / PIf);
#pragma unroll
  for (int j = 0; j < 8; ++j) {
    float d = x - j * (PIf / 7.f);
    ee[a * 16 + j] = expf(-g1 * d * d);
  }
  float y = el[asrc[a]];
  float g2 = (7.f / 4.f) * (7.f / 4.f);
#pragma unroll
  for (int j = 0; j < 8; ++j) {
    float d = y - j * (4.f / 7.f);
    ee[a * 16 + 8 + j] = expf(-g2 * d * d);
  }
}

// W[R][C] -> WT[C][R] (f32, for GRU)
__global__ void k_transpose(const float* __restrict__ W, float* __restrict__ WT,
                            int R, int C) {
  int idx = blockIdx.x * blockDim.x + threadIdx.x;
  if (idx >= R * C) return;
  int r = idx / C, c = idx % C;
  WT[c * R + r] = W[idx];
}

// Tt[n=k*64+o][i] = (k<16 ? W[k*4096 + i*64 + o] : b2[i*64+o]), fp16. n in [0,1088)
__global__ void k_maket(const float* __restrict__ W, const float* __restrict__ b2,
                        h16* __restrict__ Tt) {
  int idx = blockIdx.x * blockDim.x + threadIdx.x;
  if (idx >= 1088 * 64) return;
  int n = idx >> 6, i = idx & 63;
  int k = n >> 6, o = n & 63;
  float val = (k < 16) ? W[(size_t)k * 4096 + i * 64 + o] : b2[i * 64 + o];
  Tt[(size_t)n * 64 + i] = (h16)val;
}

// Wt[o*64+i] = W[i*64+o], fp16 (B^T layout for the 64x64 MLP GEMMs)
__global__ void k_prep_wt(const float* __restrict__ W, h16* __restrict__ Wt) {
  int idx = blockIdx.x * blockDim.x + threadIdx.x;
  if (idx >= 4096) return;
  int o = idx >> 6, i = idx & 63;
  Wt[o * 64 + i] = (h16)W[i * 64 + o];
}

__global__ void k_bounds(const int* __restrict__ gid, int* __restrict__ gstart,
                         int* __restrict__ gend) {
  int n = blockIdx.x * blockDim.x + threadIdx.x;
  if (n >= N_N) return;
  int g = gid[n];
  atomicMin(&gstart[g], n);
  atomicMax(&gend[g], n + 1);
}

// ---------------- MFMA step kernels ----------------
// Fragment maps (16x16x32 f16, verified family):
//   A[m,k]: m = lane&15, k = ks*32 + 8*(lane>>4) + j (j=0..7 contiguous)
//   B[n,k]: n = lane&15, same k map (B^T storage [N][K])
//   D[m,n]: n = lane&15, m = (lane>>4)*4 + reg

// out[e,:] = relu(v[src[e]] @ W + b) (+ amsg[e,:]) -> fp16. Wave = 32 edges.
template <bool ADD_AMSG>
__global__ __launch_bounds__(256) void k_mfma_mlp(
    const float* __restrict__ v, const int* __restrict__ src,
    const h16* __restrict__ Wt, const float* __restrict__ bias,
    const float* __restrict__ amsg, h16* __restrict__ out, int T) {
  int tid = threadIdx.x, wave = tid >> 6, lane = tid & 63;
  int l15 = lane & 15, lq = lane >> 4;
  int ib0 = blockIdx.x * 128 + wave * 32;

  h16x8 afr[2][2];
#pragma unroll
  for (int s = 0; s < 2; ++s) {
    int item = ib0 + s * 16 + l15;
    if (item >= T) item = T - 1;
    const float* vp = v + (size_t)src[item] * 64;
#pragma unroll
    for (int ks = 0; ks < 2; ++ks) {
      const float4* p = (const float4*)(vp + ks * 32 + 8 * lq);
      float4 x0 = p[0], x1 = p[1];
      h16x8 a;
      a[0] = (h16)x0.x; a[1] = (h16)x0.y; a[2] = (h16)x0.z; a[3] = (h16)x0.w;
      a[4] = (h16)x1.x; a[5] = (h16)x1.y; a[6] = (h16)x1.z; a[7] = (h16)x1.w;
      afr[s][ks] = a;
    }
  }
  h16x8 bfr[4][2];
#pragma unroll
  for (int nt = 0; nt < 4; ++nt)
#pragma unroll
    for (int ks = 0; ks < 2; ++ks)
      bfr[nt][ks] = *(const h16x8*)(Wt + (size_t)(nt * 16 + l15) * 64 + ks * 32 + 8 * lq);

  f32x4 acc[2][4];
#pragma unroll
  for (int s = 0; s < 2; ++s)
#pragma unroll
    for (int nt = 0; nt < 4; ++nt) acc[s][nt] = (f32x4){0.f, 0.f, 0.f, 0.f};
#pragma unroll
  for (int s = 0; s < 2; ++s)
#pragma unroll
    for (int nt = 0; nt < 4; ++nt)
#pragma unroll
      for (int ks = 0; ks < 2; ++ks)
        acc[s][nt] = __builtin_amdgcn_mfma_f32_16x16x32_f16(afr[s][ks], bfr[nt][ks],
                                                            acc[s][nt], 0, 0, 0);
#pragma unroll
  for (int s = 0; s < 2; ++s) {
#pragma unroll
    for (int nt = 0; nt < 4; ++nt) {
      int o = nt * 16 + l15;
      float bo = bias[o];
#pragma unroll
      for (int r = 0; r < 4; ++r) {
        int item = ib0 + s * 16 + lq * 4 + r;
        if (item < T) {
          float val = fmaxf(acc[s][nt][r] + bo, 0.f);
          if (ADD_AMSG) val += amsg[(size_t)item * 64 + o];
          out[(size_t)item * 64 + o] = (h16)val;
        }
      }
    }
  }
}

// m[a,o] = sum_{kk<17} featx[a,kk] * (v[a,:] @ Tt[kk*64+o,:]); atomic scatter to dst.
template <bool GATHER>
__global__ __launch_bounds__(256) void k_mfma_mm(
    const h16* __restrict__ v, const int* __restrict__ src,
    const float* __restrict__ feat, const h16* __restrict__ Tt,
    const int* __restrict__ dst, float* __restrict__ out, int T) {
  __shared__ float f_lds[128 * 17];
  __shared__ int dst_lds[128];
  int tid = threadIdx.x;
  int base = blockIdx.x * 128;
  for (int e = tid; e < 128 * 16; e += 256) {
    int il = e >> 4, k = e & 15;
    int g = base + il;
    if (g >= T) g = T - 1;
    f_lds[il * 17 + k] = feat[(size_t)g * 16 + k];
  }
  if (tid < 128) {
    int g = base + tid;
    if (g >= T) g = T - 1;
    dst_lds[tid] = dst[g];
  }
  __syncthreads();

  int wave = tid >> 6, lane = tid & 63;
  int l15 = lane & 15, lq = lane >> 4;
  int ibl = wave * 32;
  int ib0 = base + ibl;

  h16x8 afr[2][2];
#pragma unroll
  for (int s = 0; s < 2; ++s) {
    int item = ib0 + s * 16 + l15;
    if (item >= T) item = T - 1;
    int vi = GATHER ? src[item] : item;
    const h16* vp = v + (size_t)vi * 64;
#pragma unroll
    for (int ks = 0; ks < 2; ++ks)
      afr[s][ks] = *(const h16x8*)(vp + ks * 32 + 8 * lq);
  }

  f32x4 acc[2][4];
#pragma unroll
  for (int s = 0; s < 2; ++s)
#pragma unroll
    for (int nt = 0; nt < 4; ++nt) acc[s][nt] = (f32x4){0.f, 0.f, 0.f, 0.f};

  for (int kk = 0; kk < 16; ++kk) {
    h16x8 bfr[4][2];
#pragma unroll
    for (int nt = 0; nt < 4; ++nt)
#pragma unroll
      for (int ks = 0; ks < 2; ++ks)
        bfr[nt][ks] = *(const h16x8*)(Tt + (size_t)(kk * 64 + nt * 16 + l15) * 64 +
                                      ks * 32 + 8 * lq);
    h16x8 a2[2][2];
#pragma unroll
    for (int s = 0; s < 2; ++s) {
      h16 fs = (h16)f_lds[(ibl + s * 16 + l15) * 17 + kk];
      a2[s][0] = afr[s][0] * fs;
      a2[s][1] = afr[s][1] * fs;
    }
#pragma unroll
    for (int s = 0; s < 2; ++s)
#pragma unroll
      for (int nt = 0; nt < 4; ++nt)
#pragma unroll
        for (int ks = 0; ks < 2; ++ks)
          acc[s][nt] = __builtin_amdgcn_mfma_f32_16x16x32_f16(a2[s][ks], bfr[nt][ks],
                                                              acc[s][nt], 0, 0, 0);
  }
  // bias row (kk=16, featx=1): use raw A frags
  {
    h16x8 bfr[4][2];
#pragma unroll
    for (int nt = 0; nt < 4; ++nt)
#pragma unroll
      for (int ks = 0; ks < 2; ++ks)
        bfr[nt][ks] = *(const h16x8*)(Tt + (size_t)(16 * 64 + nt * 16 + l15) * 64 +
                                      ks * 32 + 8 * lq);
#pragma unroll
    for (int s = 0; s < 2; ++s)
#pragma unroll
      for (int nt = 0; nt < 4; ++nt)
#pragma unroll
        for (int ks = 0; ks < 2; ++ks)
          acc[s][nt] = __builtin_amdgcn_mfma_f32_16x16x32_f16(afr[s][ks], bfr[nt][ks],
                                                              acc[s][nt], 0, 0, 0);
  }

#pragma unroll
  for (int s = 0; s < 2; ++s) {
#pragma unroll
    for (int r = 0; r < 4; ++r) {
      int il = ibl + s * 16 + lq * 4 + r;
      int item = base + il;
      if (item < T) {
        float* op = out + (size_t)dst_lds[il] * 64;
#pragma unroll
        for (int nt = 0; nt < 4; ++nt)
          atomAddF(op + nt * 16 + l15, acc[s][nt][r]);
      }
    }
  }
}

// fused: x = relu(nacc + gnn_b); h' = GRU(x, h). wave per node, lane = unit
__global__ void k_gru(const float* __restrict__ nacc, const float* __restrict__ gnnb,
                      const float* __restrict__ h, const float* __restrict__ WihT,
                      const float* __restrict__ WhhT, const float* __restrict__ bih,
                      const float* __restrict__ bhh, float* __restrict__ hout) {
  int wid = (blockIdx.x * blockDim.x + threadIdx.x) >> 6;
  int lane = threadIdx.x & 63;
  if (wid >= N_N) return;
  const float* xr = nacc + (size_t)wid * 64;
  const float* hr = h + (size_t)wid * 64;
  float air = bih[lane], aiz = bih[64 + lane], ain = bih[128 + lane];
  float ahr = bhh[lane], ahz = bhh[64 + lane], ahn = bhh[128 + lane];
#pragma unroll 8
  for (int i = 0; i < 64; ++i) {
    float xi = fmaxf(xr[i] + gnnb[i], 0.f);
    float hi = hr[i];
    air = fmaf(xi, WihT[i * 192 + lane], air);
    aiz = fmaf(xi, WihT[i * 192 + 64 + lane], aiz);
    ain = fmaf(xi, WihT[i * 192 + 128 + lane], ain);
    ahr = fmaf(hi, WhhT[i * 192 + lane], ahr);
    ahz = fmaf(hi, WhhT[i * 192 + 64 + lane], ahz);
    ahn = fmaf(hi, WhhT[i * 192 + 128 + lane], ahn);
  }
  float r = sigm(air + ahr);
  float z = sigm(aiz + ahz);
  float n = tanhf(ain + r * ahn);
  hout[(size_t)wid * 64 + lane] = (1.f - z) * n + z * hr[lane];
}

__global__ void k_agg(const float* __restrict__ h, const float* __restrict__ x0,
                      float* __restrict__ agg) {
  int idx = blockIdx.x * blockDim.x + threadIdx.x;
  if (idx >= N_N * 64) return;
  int n = idx >> 6, d = idx & 63;
  agg[(size_t)n * 128 + d] = h[idx];
  agg[(size_t)n * 128 + 64 + d] = x0[idx];
}

// ---------------- Set2Set ----------------

// wave per (b,u); lanes stripe K. Coalesced weight reads + butterfly reduce.
__global__ __launch_bounds__(256) void k_lstm2(
    const float* __restrict__ x, int xdim,
    const float* __restrict__ hin, const float* __restrict__ cin,
    const float* __restrict__ Wih, const float* __restrict__ Whh,
    const float* __restrict__ bih, const float* __restrict__ bhh,
    float* __restrict__ hout, float* __restrict__ cout) {
  int w = (blockIdx.x * blockDim.x + threadIdx.x) >> 6;
  int lane = threadIdx.x & 63;
  if (w >= N_B * 128) return;
  int b = w >> 7, u = w & 127;
  float a0 = 0.f, a1 = 0.f, a2 = 0.f, a3 = 0.f;
  const float* xr = x + (size_t)b * xdim;
  for (int k = lane; k < xdim; k += 64) {
    float xv = xr[k];
    a0 = fmaf(xv, Wih[(size_t)u * xdim + k], a0);
    a1 = fmaf(xv, Wih[(size_t)(128 + u) * xdim + k], a1);
    a2 = fmaf(xv, Wih[(size_t)(256 + u) * xdim + k], a2);
    a3 = fmaf(xv, Wih[(size_t)(384 + u) * xdim + k], a3);
  }
  const float* hr = hin + (size_t)b * 128;
#pragma unroll
  for (int k0 = 0; k0 < 128; k0 += 64) {
    int k = k0 + lane;
    float hv = hr[k];
    a0 = fmaf(hv, Whh[(size_t)u * 128 + k], a0);
    a1 = fmaf(hv, Whh[(size_t)(128 + u) * 128 + k], a1);
    a2 = fmaf(hv, Whh[(size_t)(256 + u) * 128 + k], a2);
    a3 = fmaf(hv, Whh[(size_t)(384 + u) * 128 + k], a3);
  }
#pragma unroll
  for (int m = 1; m < 64; m <<= 1) {
    a0 += __shfl_xor(a0, m);
    a1 += __shfl_xor(a1, m);
    a2 += __shfl_xor(a2, m);
    a3 += __shfl_xor(a3, m);
  }
  if (lane == 0) {
    float gi = a0 + bih[u] + bhh[u];
    float gf = a1 + bih[128 + u] + bhh[128 + u];
    float gg = a2 + bih[256 + u] + bhh[256 + u];
    float go = a3 + bih[384 + u] + bhh[384 + u];
    float c2 = sigm(gf) * cin[(size_t)b * 128 + u] + sigm(gi) * tanhf(gg);
    hout[(size_t)b * 128 + u] = sigm(go) * tanhf(c2);
    cout[(size_t)b * 128 + u] = c2;
  }
}

__global__ void k_escore(const float* __restrict__ agg, const float* __restrict__ q,
                         const int* __restrict__ gid, float* __restrict__ e) {
  int wid = (blockIdx.x * blockDim.x + threadIdx.x) >> 6;
  int lane = threadIdx.x & 63;
  if (wid >= N_N) return;
  int g = gid[wid];
  float a = agg[(size_t)wid * 128 + lane] * q[g * 128 + lane] +
            agg[(size_t)wid * 128 + 64 + lane] * q[g * 128 + 64 + lane];
#pragma unroll
  for (int m = 1; m < 64; m <<= 1) a += __shfl_xor(a, m);
  if (lane == 0) e[wid] = a;
}

__global__ void k_pool(const float* __restrict__ agg, const float* __restrict__ e,
                       const int* __restrict__ gstart, const int* __restrict__ gend,
                       const float* __restrict__ h1, float* __restrict__ q_star) {
  int g = blockIdx.x;
  int s = gstart[g], t = gend[g];
  __shared__ float red[128];
  int tid = threadIdx.x;
  float m = -INFINITY;
  for (int n = s + tid; n < t; n += 128) m = fmaxf(m, e[n]);
  red[tid] = m;
  __syncthreads();
  for (int o = 64; o; o >>= 1) {
    if (tid < o) red[tid] = fmaxf(red[tid], red[tid + o]);
    __syncthreads();
  }
  m = red[0];
  __syncthreads();
  float sum = 0.f;
  for (int n = s + tid; n < t; n += 128) sum += expf(e[n] - m);
  red[tid] = sum;
  __syncthreads();
  for (int o = 64; o; o >>= 1) {
    if (tid < o) red[tid] += red[tid + o];
    __syncthreads();
  }
  float inv = (red[0] > 0.f) ? 1.f / red[0] : 0.f;
  float acc = 0.f;
  for (int n = s; n < t; ++n) acc += expf(e[n] - m) * inv * agg[(size_t)n * 128 + tid];
  q_star[(size_t)g * 256 + tid] = h1[(size_t)g * 128 + tid];
  q_star[(size_t)g * 256 + 128 + tid] = acc;
}

__global__ void k_out(const float* __restrict__ qs, const float* __restrict__ W,
                      const float* __restrict__ bias, const float* __restrict__ pa,
                      float* __restrict__ out) {
  int idx = blockIdx.x * blockDim.x + threadIdx.x;
  if (idx >= N_B * N_DH) return;
  int b = idx >> 12, d = idx & 4095;
  float acc = bias[d];
  const float* q = qs + (size_t)b * 256;
  for (int k = 0; k < 256; ++k) acc = fmaf(q[k], W[(size_t)k * 4096 + d], acc);
  float a = pa[0];
  out[idx] = acc >= 0.f ? acc : a * acc;
}

// ---------------- workspace layout (float offsets) ----------------
enum : size_t {
  OFF_X0 = 0,
  OFF_HA = OFF_X0 + (size_t)N_N * 64,
  OFF_HB = OFF_HA + (size_t)N_N * 64,
  OFF_EF = OFF_HB + (size_t)N_N * 64,
  OFF_EE = OFF_EF + (size_t)N_E * 16,
  OFF_HAE = OFF_EE + (size_t)N_A * 16,   // ha_h fp16 (uses half the slot)
  OFF_AMSG = OFF_HAE + (size_t)N_E * 64,
  OFF_HBE = OFF_AMSG + (size_t)N_E * 64, // hb_h fp16
  OFF_NACC = OFF_HBE + (size_t)N_E * 64,
  OFF_AGG = OFF_NACC + (size_t)N_N * 64,
  OFF_E = OFF_AGG + (size_t)N_N * 128,
  OFF_WIHT = OFF_E + N_N,
  OFF_WHHT = OFF_WIHT + 192 * 64,
  OFF_QSTAR = OFF_WHHT + 192 * 64,
  OFF_H0A = OFF_QSTAR + N_B * 256,
  OFF_H0B = OFF_H0A + N_B * 128,
  OFF_C0A = OFF_H0B + N_B * 128,
  OFF_C0B = OFF_C0A + N_B * 128,
  OFF_H1A = OFF_C0B + N_B * 128,
  OFF_H1B = OFF_H1A + N_B * 128,
  OFF_C1A = OFF_H1B + N_B * 128,
  OFF_C1B = OFF_C1A + N_B * 128,
  OFF_GSTART = OFF_C1B + N_B * 128,
  OFF_GEND = OFF_GSTART + N_B,
  OFF_TT_ANG = (OFF_GEND + N_B + 63) & ~(size_t)63,  // 1088*64 fp16 = 34816 floats
  OFF_TT_BOND = OFF_TT_ANG + 34816,
  OFF_WT_AU = OFF_TT_BOND + 34816,       // 4096 fp16 = 2048 floats
  OFF_WT_BU = OFF_WT_AU + 2048,
  WS_FLOATS = OFF_WT_BU + 2048
};

extern "C" void kernel_launch(void* const* d_in, const int* in_sizes, int n_in,
                              void* d_out, int out_size, void* d_ws, size_t ws_size,
                              hipStream_t stream) {
  (void)in_sizes; (void)n_in; (void)out_size; (void)ws_size;
  const float* na    = (const float*)d_in[0];
  const float* ea    = (const float*)d_in[1];
  const float* el    = (const float*)d_in[2];
  const float* ang   = (const float*)d_in[3];
  const int*   esrc  = (const int*)d_in[4];
  const int*   edst  = (const int*)d_in[5];
  const int*   asrc  = (const int*)d_in[6];
  const int*   adst  = (const int*)d_in[7];
  const int*   gid   = (const int*)d_in[8];
  const float* projW = (const float*)d_in[9];
  const float* projb = (const float*)d_in[10];
  const float* bondW = (const float*)d_in[11];
  const float* bondb = (const float*)d_in[12];
  const float* efW   = (const float*)d_in[13];
  const float* efb   = (const float*)d_in[14];
  const float* gnnb  = (const float*)d_in[15];
  const float* buW   = (const float*)d_in[16];
  const float* bub   = (const float*)d_in[17];
  const float* auW   = (const float*)d_in[18];
  const float* aub   = (const float*)d_in[19];
  const float* gWih  = (const float*)d_in[20];
  const float* gWhh  = (const float*)d_in[21];
  const float* gbih  = (const float*)d_in[22];
  const float* gbhh  = (const float*)d_in[23];
  const float* sWih0 = (const float*)d_in[24];
  const float* sWhh0 = (const float*)d_in[25];
  const float* sbih0 = (const float*)d_in[26];
  const float* sbhh0 = (const float*)d_in[27];
  const float* sWih1 = (const float*)d_in[28];
  const float* sWhh1 = (const float*)d_in[29];
  const float* sbih1 = (const float*)d_in[30];
  const float* sbhh1 = (const float*)d_in[31];
  const float* spW   = (const float*)d_in[32];
  const float* spb   = (const float*)d_in[33];
  const float* pa    = (const float*)d_in[34];
  float* out = (float*)d_out;
  float* ws = (float*)d_ws;

  float* x0   = ws + OFF_X0;
  float* hA   = ws + OFF_HA;
  float* hB   = ws + OFF_HB;
  float* ef   = ws + OFF_EF;
  float* ee   = ws + OFF_EE;
  h16*   ha_h = (h16*)(ws + OFF_HAE);
  float* amsg = ws + OFF_AMSG;
  h16*   hb_h = (h16*)(ws + OFF_HBE);
  float* nacc = ws + OFF_NACC;
  float* agg  = ws + OFF_AGG;
  float* ev   = ws + OFF_E;
  float* wihT = ws + OFF_WIHT;
  float* whhT = ws + OFF_WHHT;
  float* qstar = ws + OFF_QSTAR;
  float* h0a = ws + OFF_H0A; float* h0b = ws + OFF_H0B;
  float* c0a = ws + OFF_C0A; float* c0b = ws + OFF_C0B;
  float* h1a = ws + OFF_H1A; float* h1b = ws + OFF_H1B;
  float* c1a = ws + OFF_C1A; float* c1b = ws + OFF_C1B;
  int* gstart = (int*)(ws + OFF_GSTART);
  int* gend   = (int*)(ws + OFF_GEND);
  h16* ttA = (h16*)(ws + OFF_TT_ANG);
  h16* ttB = (h16*)(ws + OFF_TT_BOND);
  h16* wtAU = (h16*)(ws + OFF_WT_AU);
  h16* wtBU = (h16*)(ws + OFF_WT_BU);

  // ---- setup ----
  k_proj<<<(N_N * 64 + 255) / 256, 256, 0, stream>>>(na, projW, projb, x0);
  k_edgefeat<<<(N_E + 255) / 256, 256, 0, stream>>>(ea, el, ef);
  k_anglefeat<<<(N_A + 255) / 256, 256, 0, stream>>>(ang, el, asrc, ee);
  k_transpose<<<(192 * 64 + 255) / 256, 256, 0, stream>>>(gWih, wihT, 192, 64);
  k_transpose<<<(192 * 64 + 255) / 256, 256, 0, stream>>>(gWhh, whhT, 192, 64);
  k_maket<<<(1088 * 64 + 255) / 256, 256, 0, stream>>>(efW, efb, ttA);
  k_maket<<<(1088 * 64 + 255) / 256, 256, 0, stream>>>(bondW, bondb, ttB);
  k_prep_wt<<<16, 256, 0, stream>>>(auW, wtAU);
  k_prep_wt<<<16, 256, 0, stream>>>(buW, wtBU);
  hipMemsetAsync(gstart, 0x7f, N_B * sizeof(int), stream);
  hipMemsetAsync(gend, 0, N_B * sizeof(int), stream);
  k_bounds<<<(N_N + 255) / 256, 256, 0, stream>>>(gid, gstart, gend);

  // ---- message-passing steps ----
  const float* cur = x0;
  float* bufs[2] = {hA, hB};
  for (int s = 0; s < 4; ++s) {
    k_mfma_mlp<false><<<(N_E + 127) / 128, 256, 0, stream>>>(cur, esrc, wtAU, aub,
                                                             nullptr, ha_h, N_E);
    hipMemsetAsync(amsg, 0, (size_t)N_E * 64 * sizeof(float), stream);
    k_mfma_mm<true><<<(N_A + 127) / 128, 256, 0, stream>>>(ha_h, asrc, ee, ttA, adst,
                                                           amsg, N_A);
    k_mfma_mlp<true><<<(N_E + 127) / 128, 256, 0, stream>>>(cur, esrc, wtBU, bub,
                                                            amsg, hb_h, N_E);
    hipMemsetAsync(nacc, 0, (size_t)N_N * 64 * sizeof(float), stream);
    k_mfma_mm<false><<<(N_E + 127) / 128, 256, 0, stream>>>(hb_h, nullptr, ef, ttB,
                                                            edst, nacc, N_E);
    float* nxt = bufs[s & 1];
    k_gru<<<(N_N * 64 + 255) / 256, 256, 0, stream>>>(nacc, gnnb, cur, wihT, whhT,
                                                      gbih, gbhh, nxt);
    cur = nxt;
  }
  k_agg<<<(N_N * 64 + 255) / 256, 256, 0, stream>>>(cur, x0, agg);

  // ---- Set2Set ----
  hipMemsetAsync(qstar, 0, (size_t)(N_B * 256 + 8 * N_B * 128) * sizeof(float), stream);
  float *h0i = h0a, *h0o = h0b, *c0i = c0a, *c0o = c0b;
  float *h1i = h1a, *h1o = h1b, *c1i = c1a, *c1o = c1b;
  for (int it = 0; it < 3; ++it) {
    k_lstm2<<<(N_B * 128 * 64 + 255) / 256, 256, 0, stream>>>(
        qstar, 256, h0i, c0i, sWih0, sWhh0, sbih0, sbhh0, h0o, c0o);
    k_lstm2<<<(N_B * 128 * 64 + 255) / 256, 256, 0, stream>>>(
        h0o, 128, h1i, c1i, sWih1, sWhh1, sbih1, sbhh1, h1o, c1o);
    k_escore<<<(N_N * 64 + 255) / 256, 256, 0, stream>>>(agg, h1o, gid, ev);
    k_pool<<<N_B, 128, 0, stream>>>(agg, ev, gstart, gend, h1o, qstar);
    float* tmp;
    tmp = h0i; h0i = h0o; h0o = tmp;
    tmp = c0i; c0i = c0o; c0o = tmp;
    tmp = h1i; h1i = h1o; h1o = tmp;
    tmp = c1i; c1i = c1o; c1o = tmp;
  }
  k_out<<<(N_B * N_DH + 255) / 256, 256, 0, stream>>>(qstar, spW, spb, pa, out);
}

// Round 4
// 552.743 us; speedup vs baseline: 4.9057x; 1.2329x over previous
//
#include <hip/hip_runtime.h>
#include <math.h>

#define N_N 8000
#define N_E 12000
#define N_A 48000
#define N_B 64
#define N_H 64
#define N_DH 4096

typedef _Float16 h16;
typedef __attribute__((ext_vector_type(8))) _Float16 h16x8;
typedef __attribute__((ext_vector_type(4))) float f32x4;

__device__ __forceinline__ float atomAddF(float* p, float v) {
  return __hip_atomic_fetch_add(p, v, __ATOMIC_RELAXED, __HIP_MEMORY_SCOPE_AGENT);
}
__device__ __forceinline__ float sigm(float x) { return 1.f / (1.f + expf(-x)); }

// ---------------- setup kernels ----------------

// x0 = relu(node_attribute @ projW + projb); wave per node, lane = out-dim
__global__ void k_proj(const float* __restrict__ na, const float* __restrict__ W,
                       const float* __restrict__ b, float* __restrict__ x0) {
  int wid = (blockIdx.x * blockDim.x + threadIdx.x) >> 6;
  int lane = threadIdx.x & 63;
  if (wid >= N_N) return;
  const float* row = na + (size_t)wid * 110;
  float acc = b[lane];
  for (int k = 0; k < 110; ++k) acc = fmaf(row[k], W[k * 64 + lane], acc);
  x0[(size_t)wid * 64 + lane] = fmaxf(acc, 0.f);
}

// edge_feat[e] = [edge_attribute(8) | rbf(edge_length, K=8, cutoff=4)]
__global__ void k_edgefeat(const float* __restrict__ ea, const float* __restrict__ el,
                           float* __restrict__ ef) {
  int e = blockIdx.x * blockDim.x + threadIdx.x;
  if (e >= N_E) return;
  float x = el[e];
  const float g2 = (7.f / 4.f) * (7.f / 4.f);
#pragma unroll
  for (int j = 0; j < 8; ++j) ef[e * 16 + j] = ea[e * 8 + j];
#pragma unroll
  for (int j = 0; j < 8; ++j) {
    float d = x - j * (4.f / 7.f);
    ef[e * 16 + 8 + j] = expf(-g2 * d * d);
  }
}

// ee_feat[a] = [rbf(angle, 8, pi) | rbf(edge_length[angle_src], 8, 4)]
__global__ void k_anglefeat(const float* __restrict__ ang, const float* __restrict__ el,
                            const int* __restrict__ asrc, float* __restrict__ ee) {
  int a = blockIdx.x * blockDim.x + threadIdx.x;
  if (a >= N_A) return;
  const float PIf = 3.14159265358979323846f;
  float x = ang[a];
  float g1 = (7.f / PIf) * (7.f / PIf);
#pragma unroll
  for (int j = 0; j < 8; ++j) {
    float d = x - j * (PIf / 7.f);
    ee[a * 16 + j] = expf(-g1 * d * d);
  }
  float y = el[asrc[a]];
  float g2 = (7.f / 4.f) * (7.f / 4.f);
#pragma unroll
  for (int j = 0; j < 8; ++j) {
    float d = y - j * (4.f / 7.f);
    ee[a * 16 + 8 + j] = expf(-g2 * d * d);
  }
}

// W[R][C] -> WT[C][R] (f32, for GRU)
__global__ void k_transpose(const float* __restrict__ W, float* __restrict__ WT,
                            int R, int C) {
  int idx = blockIdx.x * blockDim.x + threadIdx.x;
  if (idx >= R * C) return;
  int r = idx / C, c = idx % C;
  WT[c * R + r] = W[idx];
}

// Tt[n=k*64+o][i] = (k<16 ? W[k*4096 + i*64 + o] : b2[i*64+o]), fp16. n in [0,1088)
__global__ void k_maket(const float* __restrict__ W, const float* __restrict__ b2,
                        h16* __restrict__ Tt) {
  int idx = blockIdx.x * blockDim.x + threadIdx.x;
  if (idx >= 1088 * 64) return;
  int n = idx >> 6, i = idx & 63;
  int k = n >> 6, o = n & 63;
  float val = (k < 16) ? W[(size_t)k * 4096 + i * 64 + o] : b2[i * 64 + o];
  Tt[(size_t)n * 64 + i] = (h16)val;
}

// Wt[o*64+i] = W[i*64+o], fp16 (B^T layout for the 64x64 MLP GEMMs)
__global__ void k_prep_wt(const float* __restrict__ W, h16* __restrict__ Wt) {
  int idx = blockIdx.x * blockDim.x + threadIdx.x;
  if (idx >= 4096) return;
  int o = idx >> 6, i = idx & 63;
  Wt[o * 64 + i] = (h16)W[i * 64 + o];
}

// graph_ids is sorted: run-boundary detection, no atomics.
__global__ void k_bounds2(const int* __restrict__ gid, int* __restrict__ gstart,
                          int* __restrict__ gend) {
  int n = blockIdx.x * blockDim.x + threadIdx.x;
  if (n >= N_N) return;
  int g = gid[n];
  if (n == 0 || gid[n - 1] != g) gstart[g] = n;
  if (n == N_N - 1 || gid[n + 1] != g) gend[g] = n + 1;
}

// ---------------- MFMA step kernels ----------------
// Fragment maps (16x16x32 f16, verified family):
//   A[m,k]: m = lane&15, k = ks*32 + 8*(lane>>4) + j (j=0..7 contiguous)
//   B[n,k]: n = lane&15, same k map (B^T storage [N][K])
//   D[m,n]: n = lane&15, m = (lane>>4)*4 + reg

// out[e,o-half] = relu(v[src[e]] @ W + b)[o-half] (+ amsg[e,o-half]) -> fp16.
// Wave = 32 edges x 32 outs; blockIdx.y = o-half. Also zeroes zbuf (y==0 blocks).
template <bool ADD_AMSG>
__global__ __launch_bounds__(256) void k_mfma_mlp(
    const float* __restrict__ v, const int* __restrict__ src,
    const h16* __restrict__ Wt, const float* __restrict__ bias,
    const float* __restrict__ amsg, h16* __restrict__ out, int T,
    float4* __restrict__ zbuf, int zcount4) {
  // fold the downstream accumulator zeroing into this dispatch
  if (blockIdx.y == 0 && zbuf) {
    int stride = gridDim.x * 256;
    for (int i = blockIdx.x * 256 + threadIdx.x; i < zcount4; i += stride)
      zbuf[i] = (float4){0.f, 0.f, 0.f, 0.f};
  }
  int tid = threadIdx.x, wave = tid >> 6, lane = tid & 63;
  int l15 = lane & 15, lq = lane >> 4;
  int oc = blockIdx.y;  // o-half: nt in {oc*2, oc*2+1}
  int ib0 = blockIdx.x * 128 + wave * 32;

  h16x8 afr[2][2];
#pragma unroll
  for (int s = 0; s < 2; ++s) {
    int item = ib0 + s * 16 + l15;
    if (item >= T) item = T - 1;
    const float* vp = v + (size_t)src[item] * 64;
#pragma unroll
    for (int ks = 0; ks < 2; ++ks) {
      const float4* p = (const float4*)(vp + ks * 32 + 8 * lq);
      float4 x0 = p[0], x1 = p[1];
      h16x8 a;
      a[0] = (h16)x0.x; a[1] = (h16)x0.y; a[2] = (h16)x0.z; a[3] = (h16)x0.w;
      a[4] = (h16)x1.x; a[5] = (h16)x1.y; a[6] = (h16)x1.z; a[7] = (h16)x1.w;
      afr[s][ks] = a;
    }
  }
  h16x8 bfr[2][2];
#pragma unroll
  for (int nt = 0; nt < 2; ++nt)
#pragma unroll
    for (int ks = 0; ks < 2; ++ks)
      bfr[nt][ks] = *(const h16x8*)(Wt + (size_t)((oc * 2 + nt) * 16 + l15) * 64 +
                                    ks * 32 + 8 * lq);

  f32x4 acc[2][2];
#pragma unroll
  for (int s = 0; s < 2; ++s)
#pragma unroll
    for (int nt = 0; nt < 2; ++nt) acc[s][nt] = (f32x4){0.f, 0.f, 0.f, 0.f};
#pragma unroll
  for (int s = 0; s < 2; ++s)
#pragma unroll
    for (int nt = 0; nt < 2; ++nt)
#pragma unroll
      for (int ks = 0; ks < 2; ++ks)
        acc[s][nt] = __builtin_amdgcn_mfma_f32_16x16x32_f16(afr[s][ks], bfr[nt][ks],
                                                            acc[s][nt], 0, 0, 0);
#pragma unroll
  for (int s = 0; s < 2; ++s) {
#pragma unroll
    for (int nt = 0; nt < 2; ++nt) {
      int o = (oc * 2 + nt) * 16 + l15;
      float bo = bias[o];
#pragma unroll
      for (int r = 0; r < 4; ++r) {
        int item = ib0 + s * 16 + lq * 4 + r;
        if (item < T) {
          float val = fmaxf(acc[s][nt][r] + bo, 0.f);
          if (ADD_AMSG) val += amsg[(size_t)item * 64 + o];
          out[(size_t)item * 64 + o] = (h16)val;
        }
      }
    }
  }
}

// m[a,o-half] = sum_{kk<17} featx[a,kk] * (v[a,:] @ Tt[kk*64+o,:]); atomic scatter.
// Wave = 32 items x 32 outs; blockIdx.y = o-half.
template <bool GATHER>
__global__ __launch_bounds__(256) void k_mfma_mm(
    const h16* __restrict__ v, const int* __restrict__ src,
    const float* __restrict__ feat, const h16* __restrict__ Tt,
    const int* __restrict__ dst, float* __restrict__ out, int T) {
  __shared__ float f_lds[128 * 17];
  __shared__ int dst_lds[128];
  int tid = threadIdx.x;
  int base = blockIdx.x * 128;
  int oc = blockIdx.y;  // o-half
  for (int e = tid; e < 128 * 16; e += 256) {
    int il = e >> 4, k = e & 15;
    int g = base + il;
    if (g >= T) g = T - 1;
    f_lds[il * 17 + k] = feat[(size_t)g * 16 + k];
  }
  if (tid < 128) {
    int g = base + tid;
    if (g >= T) g = T - 1;
    dst_lds[tid] = dst[g];
  }
  __syncthreads();

  int wave = tid >> 6, lane = tid & 63;
  int l15 = lane & 15, lq = lane >> 4;
  int ibl = wave * 32;
  int ib0 = base + ibl;

  h16x8 afr[2][2];
#pragma unroll
  for (int s = 0; s < 2; ++s) {
    int item = ib0 + s * 16 + l15;
    if (item >= T) item = T - 1;
    int vi = GATHER ? src[item] : item;
    const h16* vp = v + (size_t)vi * 64;
#pragma unroll
    for (int ks = 0; ks < 2; ++ks)
      afr[s][ks] = *(const h16x8*)(vp + ks * 32 + 8 * lq);
  }

  f32x4 acc[2][2];
#pragma unroll
  for (int s = 0; s < 2; ++s)
#pragma unroll
    for (int nt = 0; nt < 2; ++nt) acc[s][nt] = (f32x4){0.f, 0.f, 0.f, 0.f};

  for (int kk = 0; kk < 16; ++kk) {
    h16x8 bfr[2][2];
#pragma unroll
    for (int nt = 0; nt < 2; ++nt)
#pragma unroll
      for (int ks = 0; ks < 2; ++ks)
        bfr[nt][ks] = *(const h16x8*)(Tt + (size_t)(kk * 64 + (oc * 2 + nt) * 16 + l15) * 64 +
                                      ks * 32 + 8 * lq);
    h16x8 a2[2][2];
#pragma unroll
    for (int s = 0; s < 2; ++s) {
      h16 fs = (h16)f_lds[(ibl + s * 16 + l15) * 17 + kk];
      a2[s][0] = afr[s][0] * fs;
      a2[s][1] = afr[s][1] * fs;
    }
#pragma unroll
    for (int s = 0; s < 2; ++s)
#pragma unroll
      for (int nt = 0; nt < 2; ++nt)
#pragma unroll
        for (int ks = 0; ks < 2; ++ks)
          acc[s][nt] = __builtin_amdgcn_mfma_f32_16x16x32_f16(a2[s][ks], bfr[nt][ks],
                                                              acc[s][nt], 0, 0, 0);
  }
  // bias row (kk=16, featx=1): use raw A frags
  {
    h16x8 bfr[2][2];
#pragma unroll
    for (int nt = 0; nt < 2; ++nt)
#pragma unroll
      for (int ks = 0; ks < 2; ++ks)
        bfr[nt][ks] = *(const h16x8*)(Tt + (size_t)(16 * 64 + (oc * 2 + nt) * 16 + l15) * 64 +
                                      ks * 32 + 8 * lq);
#pragma unroll
    for (int s = 0; s < 2; ++s)
#pragma unroll
      for (int nt = 0; nt < 2; ++nt)
#pragma unroll
        for (int ks = 0; ks < 2; ++ks)
          acc[s][nt] = __builtin_amdgcn_mfma_f32_16x16x32_f16(afr[s][ks], bfr[nt][ks],
                                                              acc[s][nt], 0, 0, 0);
  }

#pragma unroll
  for (int s = 0; s < 2; ++s) {
#pragma unroll
    for (int r = 0; r < 4; ++r) {
      int il = ibl + s * 16 + lq * 4 + r;
      int item = base + il;
      if (item < T) {
        float* op = out + (size_t)dst_lds[il] * 64;
#pragma unroll
        for (int nt = 0; nt < 2; ++nt)
          atomAddF(op + (oc * 2 + nt) * 16 + l15, acc[s][nt][r]);
      }
    }
  }
}

// fused: x = relu(nacc + gnn_b); h' = GRU(x, h). wave per node, lane = unit
__global__ void k_gru(const float* __restrict__ nacc, const float* __restrict__ gnnb,
                      const float* __restrict__ h, const float* __restrict__ WihT,
                      const float* __restrict__ WhhT, const float* __restrict__ bih,
                      const float* __restrict__ bhh, float* __restrict__ hout) {
  int wid = (blockIdx.x * blockDim.x + threadIdx.x) >> 6;
  int lane = threadIdx.x & 63;
  if (wid >= N_N) return;
  const float* xr = nacc + (size_t)wid * 64;
  const float* hr = h + (size_t)wid * 64;
  float air = bih[lane], aiz = bih[64 + lane], ain = bih[128 + lane];
  float ahr = bhh[lane], ahz = bhh[64 + lane], ahn = bhh[128 + lane];
#pragma unroll 8
  for (int i = 0; i < 64; ++i) {
    float xi = fmaxf(xr[i] + gnnb[i], 0.f);
    float hi = hr[i];
    air = fmaf(xi, WihT[i * 192 + lane], air);
    aiz = fmaf(xi, WihT[i * 192 + 64 + lane], aiz);
    ain = fmaf(xi, WihT[i * 192 + 128 + lane], ain);
    ahr = fmaf(hi, WhhT[i * 192 + lane], ahr);
    ahz = fmaf(hi, WhhT[i * 192 + 64 + lane], ahz);
    ahn = fmaf(hi, WhhT[i * 192 + 128 + lane], ahn);
  }
  float r = sigm(air + ahr);
  float z = sigm(aiz + ahz);
  float n = tanhf(ain + r * ahn);
  hout[(size_t)wid * 64 + lane] = (1.f - z) * n + z * hr[lane];
}

__global__ void k_agg(const float* __restrict__ h, const float* __restrict__ x0,
                      float* __restrict__ agg) {
  int idx = blockIdx.x * blockDim.x + threadIdx.x;
  if (idx >= N_N * 64) return;
  int n = idx >> 6, d = idx & 63;
  agg[(size_t)n * 128 + d] = h[idx];
  agg[(size_t)n * 128 + 64 + d] = x0[idx];
}

// ---------------- Set2Set ----------------

// wave per (b,u); lanes stripe K. Coalesced weight reads + butterfly reduce.
__global__ __launch_bounds__(256) void k_lstm2(
    const float* __restrict__ x, int xdim,
    const float* __restrict__ hin, const float* __restrict__ cin,
    const float* __restrict__ Wih, const float* __restrict__ Whh,
    const float* __restrict__ bih, const float* __restrict__ bhh,
    float* __restrict__ hout, float* __restrict__ cout) {
  int w = (blockIdx.x * blockDim.x + threadIdx.x) >> 6;
  int lane = threadIdx.x & 63;
  if (w >= N_B * 128) return;
  int b = w >> 7, u = w & 127;
  float a0 = 0.f, a1 = 0.f, a2 = 0.f, a3 = 0.f;
  const float* xr = x + (size_t)b * xdim;
  for (int k = lane; k < xdim; k += 64) {
    float xv = xr[k];
    a0 = fmaf(xv, Wih[(size_t)u * xdim + k], a0);
    a1 = fmaf(xv, Wih[(size_t)(128 + u) * xdim + k], a1);
    a2 = fmaf(xv, Wih[(size_t)(256 + u) * xdim + k], a2);
    a3 = fmaf(xv, Wih[(size_t)(384 + u) * xdim + k], a3);
  }
  const float* hr = hin + (size_t)b * 128;
#pragma unroll
  for (int k0 = 0; k0 < 128; k0 += 64) {
    int k = k0 + lane;
    float hv = hr[k];
    a0 = fmaf(hv, Whh[(size_t)u * 128 + k], a0);
    a1 = fmaf(hv, Whh[(size_t)(128 + u) * 128 + k], a1);
    a2 = fmaf(hv, Whh[(size_t)(256 + u) * 128 + k], a2);
    a3 = fmaf(hv, Whh[(size_t)(384 + u) * 128 + k], a3);
  }
#pragma unroll
  for (int m = 1; m < 64; m <<= 1) {
    a0 += __shfl_xor(a0, m);
    a1 += __shfl_xor(a1, m);
    a2 += __shfl_xor(a2, m);
    a3 += __shfl_xor(a3, m);
  }
  if (lane == 0) {
    float gi = a0 + bih[u] + bhh[u];
    float gf = a1 + bih[128 + u] + bhh[128 + u];
    float gg = a2 + bih[256 + u] + bhh[256 + u];
    float go = a3 + bih[384 + u] + bhh[384 + u];
    float c2 = sigm(gf) * cin[(size_t)b * 128 + u] + sigm(gi) * tanhf(gg);
    hout[(size_t)b * 128 + u] = sigm(go) * tanhf(c2);
    cout[(size_t)b * 128 + u] = c2;
  }
}

__global__ void k_escore(const float* __restrict__ agg, const float* __restrict__ q,
                         const int* __restrict__ gid, float* __restrict__ e) {
  int wid = (blockIdx.x * blockDim.x + threadIdx.x) >> 6;
  int lane = threadIdx.x & 63;
  if (wid >= N_N) return;
  int g = gid[wid];
  float a = agg[(size_t)wid * 128 + lane] * q[g * 128 + lane] +
            agg[(size_t)wid * 128 + 64 + lane] * q[g * 128 + 64 + lane];
#pragma unroll
  for (int m = 1; m < 64; m <<= 1) a += __shfl_xor(a, m);
  if (lane == 0) e[wid] = a;
}

__global__ void k_pool(const float* __restrict__ agg, const float* __restrict__ e,
                       const int* __restrict__ gstart, const int* __restrict__ gend,
                       const float* __restrict__ h1, float* __restrict__ q_star) {
  int g = blockIdx.x;
  int s = gstart[g], t = gend[g];
  __shared__ float red[128];
  int tid = threadIdx.x;
  float m = -INFINITY;
  for (int n = s + tid; n < t; n += 128) m = fmaxf(m, e[n]);
  red[tid] = m;
  __syncthreads();
  for (int o = 64; o; o >>= 1) {
    if (tid < o) red[tid] = fmaxf(red[tid], red[tid + o]);
    __syncthreads();
  }
  m = red[0];
  __syncthreads();
  float sum = 0.f;
  for (int n = s + tid; n < t; n += 128) sum += expf(e[n] - m);
  red[tid] = sum;
  __syncthreads();
  for (int o = 64; o; o >>= 1) {
    if (tid < o) red[tid] += red[tid + o];
    __syncthreads();
  }
  float inv = (red[0] > 0.f) ? 1.f / red[0] : 0.f;
  float acc = 0.f;
  for (int n = s; n < t; ++n) acc += expf(e[n] - m) * inv * agg[(size_t)n * 128 + tid];
  q_star[(size_t)g * 256 + tid] = h1[(size_t)g * 128 + tid];
  q_star[(size_t)g * 256 + 128 + tid] = acc;
}

__global__ void k_out(const float* __restrict__ qs, const float* __restrict__ W,
                      const float* __restrict__ bias, const float* __restrict__ pa,
                      float* __restrict__ out) {
  int idx = blockIdx.x * blockDim.x + threadIdx.x;
  if (idx >= N_B * N_DH) return;
  int b = idx >> 12, d = idx & 4095;
  float acc = bias[d];
  const float* q = qs + (size_t)b * 256;
  for (int k = 0; k < 256; ++k) acc = fmaf(q[k], W[(size_t)k * 4096 + d], acc);
  float a = pa[0];
  out[idx] = acc >= 0.f ? acc : a * acc;
}

// ---------------- workspace layout (float offsets) ----------------
enum : size_t {
  OFF_X0 = 0,
  OFF_HA = OFF_X0 + (size_t)N_N * 64,
  OFF_HB = OFF_HA + (size_t)N_N * 64,
  OFF_EF = OFF_HB + (size_t)N_N * 64,
  OFF_EE = OFF_EF + (size_t)N_E * 16,
  OFF_HAE = OFF_EE + (size_t)N_A * 16,   // ha_h fp16 (uses half the slot)
  OFF_AMSG = OFF_HAE + (size_t)N_E * 64,
  OFF_HBE = OFF_AMSG + (size_t)N_E * 64, // hb_h fp16
  OFF_NACC = OFF_HBE + (size_t)N_E * 64,
  OFF_AGG = OFF_NACC + (size_t)N_N * 64,
  OFF_E = OFF_AGG + (size_t)N_N * 128,
  OFF_WIHT = OFF_E + N_N,
  OFF_WHHT = OFF_WIHT + 192 * 64,
  OFF_QSTAR = OFF_WHHT + 192 * 64,
  OFF_H0A = OFF_QSTAR + N_B * 256,
  OFF_H0B = OFF_H0A + N_B * 128,
  OFF_C0A = OFF_H0B + N_B * 128,
  OFF_C0B = OFF_C0A + N_B * 128,
  OFF_H1A = OFF_C0B + N_B * 128,
  OFF_H1B = OFF_H1A + N_B * 128,
  OFF_C1A = OFF_H1B + N_B * 128,
  OFF_C1B = OFF_C1A + N_B * 128,
  OFF_GSTART = OFF_C1B + N_B * 128,
  OFF_GEND = OFF_GSTART + N_B,
  OFF_TT_ANG = (OFF_GEND + N_B + 63) & ~(size_t)63,  // 1088*64 fp16 = 34816 floats
  OFF_TT_BOND = OFF_TT_ANG + 34816,
  OFF_WT_AU = OFF_TT_BOND + 34816,       // 4096 fp16 = 2048 floats
  OFF_WT_BU = OFF_WT_AU + 2048,
  WS_FLOATS = OFF_WT_BU + 2048
};

extern "C" void kernel_launch(void* const* d_in, const int* in_sizes, int n_in,
                              void* d_out, int out_size, void* d_ws, size_t ws_size,
                              hipStream_t stream) {
  (void)in_sizes; (void)n_in; (void)out_size; (void)ws_size;
  const float* na    = (const float*)d_in[0];
  const float* ea    = (const float*)d_in[1];
  const float* el    = (const float*)d_in[2];
  const float* ang   = (const float*)d_in[3];
  const int*   esrc  = (const int*)d_in[4];
  const int*   edst  = (const int*)d_in[5];
  const int*   asrc  = (const int*)d_in[6];
  const int*   adst  = (const int*)d_in[7];
  const int*   gid   = (const int*)d_in[8];
  const float* projW = (const float*)d_in[9];
  const float* projb = (const float*)d_in[10];
  const float* bondW = (const float*)d_in[11];
  const float* bondb = (const float*)d_in[12];
  const float* efW   = (const float*)d_in[13];
  const float* efb   = (const float*)d_in[14];
  const float* gnnb  = (const float*)d_in[15];
  const float* buW   = (const float*)d_in[16];
  const float* bub   = (const float*)d_in[17];
  const float* auW   = (const float*)d_in[18];
  const float* aub   = (const float*)d_in[19];
  const float* gWih  = (const float*)d_in[20];
  const float* gWhh  = (const float*)d_in[21];
  const float* gbih  = (const float*)d_in[22];
  const float* gbhh  = (const float*)d_in[23];
  const float* sWih0 = (const float*)d_in[24];
  const float* sWhh0 = (const float*)d_in[25];
  const float* sbih0 = (const float*)d_in[26];
  const float* sbhh0 = (const float*)d_in[27];
  const float* sWih1 = (const float*)d_in[28];
  const float* sWhh1 = (const float*)d_in[29];
  const float* sbih1 = (const float*)d_in[30];
  const float* sbhh1 = (const float*)d_in[31];
  const float* spW   = (const float*)d_in[32];
  const float* spb   = (const float*)d_in[33];
  const float* pa    = (const float*)d_in[34];
  float* out = (float*)d_out;
  float* ws = (float*)d_ws;

  float* x0   = ws + OFF_X0;
  float* hA   = ws + OFF_HA;
  float* hB   = ws + OFF_HB;
  float* ef   = ws + OFF_EF;
  float* ee   = ws + OFF_EE;
  h16*   ha_h = (h16*)(ws + OFF_HAE);
  float* amsg = ws + OFF_AMSG;
  h16*   hb_h = (h16*)(ws + OFF_HBE);
  float* nacc = ws + OFF_NACC;
  float* agg  = ws + OFF_AGG;
  float* ev   = ws + OFF_E;
  float* wihT = ws + OFF_WIHT;
  float* whhT = ws + OFF_WHHT;
  float* qstar = ws + OFF_QSTAR;
  float* h0a = ws + OFF_H0A; float* h0b = ws + OFF_H0B;
  float* c0a = ws + OFF_C0A; float* c0b = ws + OFF_C0B;
  float* h1a = ws + OFF_H1A; float* h1b = ws + OFF_H1B;
  float* c1a = ws + OFF_C1A; float* c1b = ws + OFF_C1B;
  int* gstart = (int*)(ws + OFF_GSTART);
  int* gend   = (int*)(ws + OFF_GEND);
  h16* ttA = (h16*)(ws + OFF_TT_ANG);
  h16* ttB = (h16*)(ws + OFF_TT_BOND);
  h16* wtAU = (h16*)(ws + OFF_WT_AU);
  h16* wtBU = (h16*)(ws + OFF_WT_BU);

  // ---- setup ----
  k_proj<<<(N_N * 64 + 255) / 256, 256, 0, stream>>>(na, projW, projb, x0);
  k_edgefeat<<<(N_E + 255) / 256, 256, 0, stream>>>(ea, el, ef);
  k_anglefeat<<<(N_A + 255) / 256, 256, 0, stream>>>(ang, el, asrc, ee);
  k_transpose<<<(192 * 64 + 255) / 256, 256, 0, stream>>>(gWih, wihT, 192, 64);
  k_transpose<<<(192 * 64 + 255) / 256, 256, 0, stream>>>(gWhh, whhT, 192, 64);
  k_maket<<<(1088 * 64 + 255) / 256, 256, 0, stream>>>(efW, efb, ttA);
  k_maket<<<(1088 * 64 + 255) / 256, 256, 0, stream>>>(bondW, bondb, ttB);
  k_prep_wt<<<16, 256, 0, stream>>>(auW, wtAU);
  k_prep_wt<<<16, 256, 0, stream>>>(buW, wtBU);
  hipMemsetAsync(gstart, 0x7f, N_B * sizeof(int), stream);
  hipMemsetAsync(gend, 0, N_B * sizeof(int), stream);
  k_bounds2<<<(N_N + 255) / 256, 256, 0, stream>>>(gid, gstart, gend);

  // ---- message-passing steps ----
  const int MLP_GX = (N_E + 127) / 128;
  const float* cur = x0;
  float* bufs[2] = {hA, hB};
  for (int s = 0; s < 4; ++s) {
    // zeroes amsg (y==0 blocks), then computes ha
    k_mfma_mlp<false><<<dim3(MLP_GX, 2), 256, 0, stream>>>(
        cur, esrc, wtAU, aub, nullptr, ha_h, N_E, (float4*)amsg, N_E * 64 / 4);
    k_mfma_mm<true><<<dim3((N_A + 127) / 128, 2), 256, 0, stream>>>(
        ha_h, asrc, ee, ttA, adst, amsg, N_A);
    // zeroes nacc (y==0 blocks), then computes hb = relu(..)+amsg
    k_mfma_mlp<true><<<dim3(MLP_GX, 2), 256, 0, stream>>>(
        cur, esrc, wtBU, bub, amsg, hb_h, N_E, (float4*)nacc, N_N * 64 / 4);
    k_mfma_mm<false><<<dim3(MLP_GX, 2), 256, 0, stream>>>(
        hb_h, nullptr, ef, ttB, edst, nacc, N_E);
    float* nxt = bufs[s & 1];
    k_gru<<<(N_N * 64 + 255) / 256, 256, 0, stream>>>(nacc, gnnb, cur, wihT, whhT,
                                                      gbih, gbhh, nxt);
    cur = nxt;
  }
  k_agg<<<(N_N * 64 + 255) / 256, 256, 0, stream>>>(cur, x0, agg);

  // ---- Set2Set ----
  hipMemsetAsync(qstar, 0, (size_t)(N_B * 256 + 8 * N_B * 128) * sizeof(float), stream);
  float *h0i = h0a, *h0o = h0b, *c0i = c0a, *c0o = c0b;
  float *h1i = h1a, *h1o = h1b, *c1i = c1a, *c1o = c1b;
  for (int it = 0; it < 3; ++it) {
    k_lstm2<<<(N_B * 128 * 64 + 255) / 256, 256, 0, stream>>>(
        qstar, 256, h0i, c0i, sWih0, sWhh0, sbih0, sbhh0, h0o, c0o);
    k_lstm2<<<(N_B * 128 * 64 + 255) / 256, 256, 0, stream>>>(
        h0o, 128, h1i, c1i, sWih1, sWhh1, sbih1, sbhh1, h1o, c1o);
    k_escore<<<(N_N * 64 + 255) / 256, 256, 0, stream>>>(agg, h1o, gid, ev);
    k_pool<<<N_B, 128, 0, stream>>>(agg, ev, gstart, gend, h1o, qstar);
    float* tmp;
    tmp = h0i; h0i = h0o; h0o = tmp;
    tmp = c0i; c0i = c0o; c0o = tmp;
    tmp = h1i; h1i = h1o; h1o = tmp;
    tmp = c1i; c1i = c1o; c1o = tmp;
  }
  k_out<<<(N_B * N_DH + 255) / 256, 256, 0, stream>>>(qstar, spW, spb, pa, out);
}

// Round 5
// 460.033 us; speedup vs baseline: 5.8944x; 1.2015x over previous
//
#include <hip/hip_runtime.h>
#include <math.h>

#define N_N 8000
#define N_E 12000
#define N_A 48000
#define N_B 64
#define N_H 64
#define N_DH 4096

typedef _Float16 h16;
typedef __attribute__((ext_vector_type(8))) _Float16 h16x8;
typedef __attribute__((ext_vector_type(4))) float f32x4;

__device__ __forceinline__ float atomAddF(float* p, float v) {
  return __hip_atomic_fetch_add(p, v, __ATOMIC_RELAXED, __HIP_MEMORY_SCOPE_AGENT);
}
__device__ __forceinline__ float sigm(float x) { return 1.f / (1.f + expf(-x)); }

// ---------------- setup kernels ----------------

// x0 = relu(node_attribute @ projW + projb); wave per node, lane = out-dim
__global__ void k_proj(const float* __restrict__ na, const float* __restrict__ W,
                       const float* __restrict__ b, float* __restrict__ x0) {
  int wid = (blockIdx.x * blockDim.x + threadIdx.x) >> 6;
  int lane = threadIdx.x & 63;
  if (wid >= N_N) return;
  const float* row = na + (size_t)wid * 110;
  float acc = b[lane];
  for (int k = 0; k < 110; ++k) acc = fmaf(row[k], W[k * 64 + lane], acc);
  x0[(size_t)wid * 64 + lane] = fmaxf(acc, 0.f);
}

// edge_feat + ee_feat in one dispatch
__global__ void k_feat(const float* __restrict__ ea, const float* __restrict__ el,
                       const float* __restrict__ ang, const int* __restrict__ asrc,
                       float* __restrict__ ef, float* __restrict__ ee) {
  int i = blockIdx.x * blockDim.x + threadIdx.x;
  const float g2 = (7.f / 4.f) * (7.f / 4.f);
  if (i < N_E) {
    int e = i;
    float x = el[e];
#pragma unroll
    for (int j = 0; j < 8; ++j) ef[e * 16 + j] = ea[e * 8 + j];
#pragma unroll
    for (int j = 0; j < 8; ++j) {
      float d = x - j * (4.f / 7.f);
      ef[e * 16 + 8 + j] = expf(-g2 * d * d);
    }
  } else if (i < N_E + N_A) {
    int a = i - N_E;
    const float PIf = 3.14159265358979323846f;
    float x = ang[a];
    float g1 = (7.f / PIf) * (7.f / PIf);
#pragma unroll
    for (int j = 0; j < 8; ++j) {
      float d = x - j * (PIf / 7.f);
      ee[a * 16 + j] = expf(-g1 * d * d);
    }
    float y = el[asrc[a]];
#pragma unroll
    for (int j = 0; j < 8; ++j) {
      float d = y - j * (4.f / 7.f);
      ee[a * 16 + 8 + j] = expf(-g2 * d * d);
    }
  }
}

// One prep dispatch builds all fp16 weight layouts:
//   W3t [256][128]: GRU combined (r|z fused x+h, in x-only, hn h-only)
//   ttA/ttB [1088][64]: per-feature weight tensors + bias row
//   wtAU/wtBU [64][64]: B^T for the 64x64 MLPs
#define PREP_B0 32768
#define PREP_B1 (PREP_B0 + 69632)
#define PREP_B2 (PREP_B1 + 69632)
#define PREP_B3 (PREP_B2 + 4096)
#define PREP_B4 (PREP_B3 + 4096)
__global__ void k_prep(const float* __restrict__ gWih, const float* __restrict__ gWhh,
                       const float* __restrict__ efW, const float* __restrict__ efb,
                       const float* __restrict__ bondW, const float* __restrict__ bondb,
                       const float* __restrict__ auW, const float* __restrict__ buW,
                       h16* __restrict__ W3t, h16* __restrict__ ttA,
                       h16* __restrict__ ttB, h16* __restrict__ wtAU,
                       h16* __restrict__ wtBU) {
  int i = blockIdx.x * blockDim.x + threadIdx.x;
  if (i < PREP_B0) {
    int col = i >> 7, k = i & 127;
    int grp = col >> 6, u = col & 63;
    float v;
    if (grp == 0) v = (k < 64) ? gWih[u * 64 + k] : gWhh[u * 64 + k - 64];
    else if (grp == 1) v = (k < 64) ? gWih[(64 + u) * 64 + k] : gWhh[(64 + u) * 64 + k - 64];
    else if (grp == 2) v = (k < 64) ? gWih[(128 + u) * 64 + k] : 0.f;
    else v = (k < 64) ? 0.f : gWhh[(128 + u) * 64 + k - 64];
    W3t[i] = (h16)v;
  } else if (i < PREP_B1) {
    int j = i - PREP_B0;
    int n = j >> 6, i2 = j & 63;
    int k = n >> 6, o = n & 63;
    float val = (k < 16) ? efW[(size_t)k * 4096 + i2 * 64 + o] : efb[i2 * 64 + o];
    ttA[j] = (h16)val;
  } else if (i < PREP_B2) {
    int j = i - PREP_B1;
    int n = j >> 6, i2 = j & 63;
    int k = n >> 6, o = n & 63;
    float val = (k < 16) ? bondW[(size_t)k * 4096 + i2 * 64 + o] : bondb[i2 * 64 + o];
    ttB[j] = (h16)val;
  } else if (i < PREP_B3) {
    int j = i - PREP_B2;
    int o = j >> 6, i2 = j & 63;
    wtAU[j] = (h16)auW[i2 * 64 + o];
  } else if (i < PREP_B4) {
    int j = i - PREP_B3;
    int o = j >> 6, i2 = j & 63;
    wtBU[j] = (h16)buW[i2 * 64 + o];
  }
}

// graph_ids is sorted: run-boundary detection, no atomics.
__global__ void k_bounds2(const int* __restrict__ gid, int* __restrict__ gstart,
                          int* __restrict__ gend) {
  int n = blockIdx.x * blockDim.x + threadIdx.x;
  if (n >= N_N) return;
  int g = gid[n];
  if (n == 0 || gid[n - 1] != g) gstart[g] = n;
  if (n == N_N - 1 || gid[n + 1] != g) gend[g] = n + 1;
}

// ---------------- MFMA step kernels ----------------
// Fragment maps (16x16x32 f16, verified family):
//   A[m,k]: m = lane&15, k = ks*32 + 8*(lane>>4) + j (j=0..7 contiguous)
//   B[n,k]: n = lane&15, same k map (B^T storage [N][K])
//   D[m,n]: n = lane&15, m = (lane>>4)*4 + reg

// out[e,o-half] = relu(v[src[e]] @ W + b)[o-half] (+ amsg[e,o-half]) -> fp16.
// Wave = 32 edges x 32 outs; blockIdx.y = o-half. Also zeroes zbuf (y==0 blocks).
template <bool ADD_AMSG>
__global__ __launch_bounds__(256) void k_mfma_mlp(
    const float* __restrict__ v, const int* __restrict__ src,
    const h16* __restrict__ Wt, const float* __restrict__ bias,
    const float* __restrict__ amsg, h16* __restrict__ out, int T,
    float4* __restrict__ zbuf, int zcount4) {
  if (blockIdx.y == 0 && zbuf) {
    int stride = gridDim.x * 256;
    for (int i = blockIdx.x * 256 + threadIdx.x; i < zcount4; i += stride)
      zbuf[i] = (float4){0.f, 0.f, 0.f, 0.f};
  }
  int tid = threadIdx.x, wave = tid >> 6, lane = tid & 63;
  int l15 = lane & 15, lq = lane >> 4;
  int oc = blockIdx.y;
  int ib0 = blockIdx.x * 128 + wave * 32;

  h16x8 afr[2][2];
#pragma unroll
  for (int s = 0; s < 2; ++s) {
    int item = ib0 + s * 16 + l15;
    if (item >= T) item = T - 1;
    const float* vp = v + (size_t)src[item] * 64;
#pragma unroll
    for (int ks = 0; ks < 2; ++ks) {
      const float4* p = (const float4*)(vp + ks * 32 + 8 * lq);
      float4 x0 = p[0], x1 = p[1];
      h16x8 a;
      a[0] = (h16)x0.x; a[1] = (h16)x0.y; a[2] = (h16)x0.z; a[3] = (h16)x0.w;
      a[4] = (h16)x1.x; a[5] = (h16)x1.y; a[6] = (h16)x1.z; a[7] = (h16)x1.w;
      afr[s][ks] = a;
    }
  }
  h16x8 bfr[2][2];
#pragma unroll
  for (int nt = 0; nt < 2; ++nt)
#pragma unroll
    for (int ks = 0; ks < 2; ++ks)
      bfr[nt][ks] = *(const h16x8*)(Wt + (size_t)((oc * 2 + nt) * 16 + l15) * 64 +
                                    ks * 32 + 8 * lq);

  f32x4 acc[2][2];
#pragma unroll
  for (int s = 0; s < 2; ++s)
#pragma unroll
    for (int nt = 0; nt < 2; ++nt) acc[s][nt] = (f32x4){0.f, 0.f, 0.f, 0.f};
#pragma unroll
  for (int s = 0; s < 2; ++s)
#pragma unroll
    for (int nt = 0; nt < 2; ++nt)
#pragma unroll
      for (int ks = 0; ks < 2; ++ks)
        acc[s][nt] = __builtin_amdgcn_mfma_f32_16x16x32_f16(afr[s][ks], bfr[nt][ks],
                                                            acc[s][nt], 0, 0, 0);
#pragma unroll
  for (int s = 0; s < 2; ++s) {
#pragma unroll
    for (int nt = 0; nt < 2; ++nt) {
      int o = (oc * 2 + nt) * 16 + l15;
      float bo = bias[o];
#pragma unroll
      for (int r = 0; r < 4; ++r) {
        int item = ib0 + s * 16 + lq * 4 + r;
        if (item < T) {
          float val = fmaxf(acc[s][nt][r] + bo, 0.f);
          if (ADD_AMSG) val += amsg[(size_t)item * 64 + o];
          out[(size_t)item * 64 + o] = (h16)val;
        }
      }
    }
  }
}

// m[a,o-half] = sum_{kk<17} featx[a,kk] * (v[a,:] @ Tt[kk*64+o,:]); atomic scatter.
template <bool GATHER>
__global__ __launch_bounds__(256) void k_mfma_mm(
    const h16* __restrict__ v, const int* __restrict__ src,
    const float* __restrict__ feat, const h16* __restrict__ Tt,
    const int* __restrict__ dst, float* __restrict__ out, int T) {
  __shared__ float f_lds[128 * 17];
  __shared__ int dst_lds[128];
  int tid = threadIdx.x;
  int base = blockIdx.x * 128;
  int oc = blockIdx.y;
  for (int e = tid; e < 128 * 16; e += 256) {
    int il = e >> 4, k = e & 15;
    int g = base + il;
    if (g >= T) g = T - 1;
    f_lds[il * 17 + k] = feat[(size_t)g * 16 + k];
  }
  if (tid < 128) {
    int g = base + tid;
    if (g >= T) g = T - 1;
    dst_lds[tid] = dst[g];
  }
  __syncthreads();

  int wave = tid >> 6, lane = tid & 63;
  int l15 = lane & 15, lq = lane >> 4;
  int ibl = wave * 32;
  int ib0 = base + ibl;

  h16x8 afr[2][2];
#pragma unroll
  for (int s = 0; s < 2; ++s) {
    int item = ib0 + s * 16 + l15;
    if (item >= T) item = T - 1;
    int vi = GATHER ? src[item] : item;
    const h16* vp = v + (size_t)vi * 64;
#pragma unroll
    for (int ks = 0; ks < 2; ++ks)
      afr[s][ks] = *(const h16x8*)(vp + ks * 32 + 8 * lq);
  }

  f32x4 acc[2][2];
#pragma unroll
  for (int s = 0; s < 2; ++s)
#pragma unroll
    for (int nt = 0; nt < 2; ++nt) acc[s][nt] = (f32x4){0.f, 0.f, 0.f, 0.f};

  for (int kk = 0; kk < 16; ++kk) {
    h16x8 bfr[2][2];
#pragma unroll
    for (int nt = 0; nt < 2; ++nt)
#pragma unroll
      for (int ks = 0; ks < 2; ++ks)
        bfr[nt][ks] = *(const h16x8*)(Tt + (size_t)(kk * 64 + (oc * 2 + nt) * 16 + l15) * 64 +
                                      ks * 32 + 8 * lq);
    h16x8 a2[2][2];
#pragma unroll
    for (int s = 0; s < 2; ++s) {
      h16 fs = (h16)f_lds[(ibl + s * 16 + l15) * 17 + kk];
      a2[s][0] = afr[s][0] * fs;
      a2[s][1] = afr[s][1] * fs;
    }
#pragma unroll
    for (int s = 0; s < 2; ++s)
#pragma unroll
      for (int nt = 0; nt < 2; ++nt)
#pragma unroll
        for (int ks = 0; ks < 2; ++ks)
          acc[s][nt] = __builtin_amdgcn_mfma_f32_16x16x32_f16(a2[s][ks], bfr[nt][ks],
                                                              acc[s][nt], 0, 0, 0);
  }
  {
    h16x8 bfr[2][2];
#pragma unroll
    for (int nt = 0; nt < 2; ++nt)
#pragma unroll
      for (int ks = 0; ks < 2; ++ks)
        bfr[nt][ks] = *(const h16x8*)(Tt + (size_t)(16 * 64 + (oc * 2 + nt) * 16 + l15) * 64 +
                                      ks * 32 + 8 * lq);
#pragma unroll
    for (int s = 0; s < 2; ++s)
#pragma unroll
      for (int nt = 0; nt < 2; ++nt)
#pragma unroll
        for (int ks = 0; ks < 2; ++ks)
          acc[s][nt] = __builtin_amdgcn_mfma_f32_16x16x32_f16(afr[s][ks], bfr[nt][ks],
                                                              acc[s][nt], 0, 0, 0);
  }

#pragma unroll
  for (int s = 0; s < 2; ++s) {
#pragma unroll
    for (int r = 0; r < 4; ++r) {
      int il = ibl + s * 16 + lq * 4 + r;
      int item = base + il;
      if (item < T) {
        float* op = out + (size_t)dst_lds[il] * 64;
#pragma unroll
        for (int nt = 0; nt < 2; ++nt)
          atomAddF(op + (oc * 2 + nt) * 16 + l15, acc[s][nt][r]);
      }
    }
  }
}

// MFMA GRU: gates = [relu(nacc+gnnb) | h] @ W3t^T (256 cols), epilogue applies GRU.
// Wave = 16 nodes; block = 4 waves = 64 nodes. Optionally writes agg rows.
__global__ __launch_bounds__(256) void k_gru2(
    const float* __restrict__ nacc, const float* __restrict__ gnnb,
    const float* __restrict__ h, const h16* __restrict__ W3t,
    const float* __restrict__ gbih, const float* __restrict__ gbhh,
    float* __restrict__ hout, const float* __restrict__ x0,
    float* __restrict__ agg, int wagg) {
  int tid = threadIdx.x, wave = tid >> 6, lane = tid & 63;
  int l15 = lane & 15, lq = lane >> 4;
  int ib0 = blockIdx.x * 64 + wave * 16;
  int nodeA = ib0 + l15;
  if (nodeA >= N_N) nodeA = N_N - 1;

  h16x8 afr[4];
#pragma unroll
  for (int ks = 0; ks < 2; ++ks) {
    const float4* p = (const float4*)(nacc + (size_t)nodeA * 64 + ks * 32 + 8 * lq);
    const float4* gp = (const float4*)(gnnb + ks * 32 + 8 * lq);
    float4 v0 = p[0], v1 = p[1], g0 = gp[0], g1 = gp[1];
    h16x8 a;
    a[0] = (h16)fmaxf(v0.x + g0.x, 0.f); a[1] = (h16)fmaxf(v0.y + g0.y, 0.f);
    a[2] = (h16)fmaxf(v0.z + g0.z, 0.f); a[3] = (h16)fmaxf(v0.w + g0.w, 0.f);
    a[4] = (h16)fmaxf(v1.x + g1.x, 0.f); a[5] = (h16)fmaxf(v1.y + g1.y, 0.f);
    a[6] = (h16)fmaxf(v1.z + g1.z, 0.f); a[7] = (h16)fmaxf(v1.w + g1.w, 0.f);
    afr[ks] = a;
  }
#pragma unroll
  for (int ks = 0; ks < 2; ++ks) {
    const float4* p = (const float4*)(h + (size_t)nodeA * 64 + ks * 32 + 8 * lq);
    float4 v0 = p[0], v1 = p[1];
    h16x8 a;
    a[0] = (h16)v0.x; a[1] = (h16)v0.y; a[2] = (h16)v0.z; a[3] = (h16)v0.w;
    a[4] = (h16)v1.x; a[5] = (h16)v1.y; a[6] = (h16)v1.z; a[7] = (h16)v1.w;
    afr[2 + ks] = a;
  }

  f32x4 acc[16];
#pragma unroll
  for (int nt = 0; nt < 16; ++nt) acc[nt] = (f32x4){0.f, 0.f, 0.f, 0.f};
  // cols 0-127 (r,z): full K=128; cols 128-191 (in): x-part only; 192-255 (hn): h-part only
#pragma unroll
  for (int nt = 0; nt < 16; ++nt) {
#pragma unroll
    for (int ks = 0; ks < 4; ++ks) {
      if (nt >= 8 && nt < 12 && ks >= 2) continue;
      if (nt >= 12 && ks < 2) continue;
      h16x8 b = *(const h16x8*)(W3t + (size_t)(nt * 16 + l15) * 128 + ks * 32 + 8 * lq);
      acc[nt] = __builtin_amdgcn_mfma_f32_16x16x32_f16(afr[ks], b, acc[nt], 0, 0, 0);
    }
  }

#pragma unroll
  for (int nt0 = 0; nt0 < 4; ++nt0) {
    int u = nt0 * 16 + l15;
    float br = gbih[u] + gbhh[u];
    float bz = gbih[64 + u] + gbhh[64 + u];
    float bin_ = gbih[128 + u];
    float bhn = gbhh[128 + u];
#pragma unroll
    for (int r = 0; r < 4; ++r) {
      int node = ib0 + lq * 4 + r;
      if (node < N_N) {
        float rr = sigm(acc[nt0][r] + br);
        float zz = sigm(acc[nt0 + 4][r] + bz);
        float nn = tanhf(acc[nt0 + 8][r] + bin_ + rr * (acc[nt0 + 12][r] + bhn));
        float hv = h[(size_t)node * 64 + u];
        float val = (1.f - zz) * nn + zz * hv;
        hout[(size_t)node * 64 + u] = val;
        if (wagg) {
          agg[(size_t)node * 128 + u] = val;
          agg[(size_t)node * 128 + 64 + u] = x0[(size_t)node * 64 + u];
        }
      }
    }
  }
}

// ---------------- Set2Set ----------------

// wave per (b,u); lanes stripe K. Coalesced weight reads + butterfly reduce.
__global__ __launch_bounds__(256) void k_lstm2(
    const float* __restrict__ x, int xdim,
    const float* __restrict__ hin, const float* __restrict__ cin,
    const float* __restrict__ Wih, const float* __restrict__ Whh,
    const float* __restrict__ bih, const float* __restrict__ bhh,
    float* __restrict__ hout, float* __restrict__ cout) {
  int w = (blockIdx.x * blockDim.x + threadIdx.x) >> 6;
  int lane = threadIdx.x & 63;
  if (w >= N_B * 128) return;
  int b = w >> 7, u = w & 127;
  float a0 = 0.f, a1 = 0.f, a2 = 0.f, a3 = 0.f;
  const float* xr = x + (size_t)b * xdim;
  for (int k = lane; k < xdim; k += 64) {
    float xv = xr[k];
    a0 = fmaf(xv, Wih[(size_t)u * xdim + k], a0);
    a1 = fmaf(xv, Wih[(size_t)(128 + u) * xdim + k], a1);
    a2 = fmaf(xv, Wih[(size_t)(256 + u) * xdim + k], a2);
    a3 = fmaf(xv, Wih[(size_t)(384 + u) * xdim + k], a3);
  }
  const float* hr = hin + (size_t)b * 128;
#pragma unroll
  for (int k0 = 0; k0 < 128; k0 += 64) {
    int k = k0 + lane;
    float hv = hr[k];
    a0 = fmaf(hv, Whh[(size_t)u * 128 + k], a0);
    a1 = fmaf(hv, Whh[(size_t)(128 + u) * 128 + k], a1);
    a2 = fmaf(hv, Whh[(size_t)(256 + u) * 128 + k], a2);
    a3 = fmaf(hv, Whh[(size_t)(384 + u) * 128 + k], a3);
  }
#pragma unroll
  for (int m = 1; m < 64; m <<= 1) {
    a0 += __shfl_xor(a0, m);
    a1 += __shfl_xor(a1, m);
    a2 += __shfl_xor(a2, m);
    a3 += __shfl_xor(a3, m);
  }
  if (lane == 0) {
    float gi = a0 + bih[u] + bhh[u];
    float gf = a1 + bih[128 + u] + bhh[128 + u];
    float gg = a2 + bih[256 + u] + bhh[256 + u];
    float go = a3 + bih[384 + u] + bhh[384 + u];
    float c2 = sigm(gf) * cin[(size_t)b * 128 + u] + sigm(gi) * tanhf(gg);
    hout[(size_t)b * 128 + u] = sigm(go) * tanhf(c2);
    cout[(size_t)b * 128 + u] = c2;
  }
}

// per-graph: scores + softmax + readout + q_star write, one block per graph.
__global__ __launch_bounds__(256) void k_pool2(
    const float* __restrict__ agg, const int* __restrict__ gstart,
    const int* __restrict__ gend, const float* __restrict__ q,
    float* __restrict__ q_star) {
  int g = blockIdx.x;
  int s = gstart[g], t = gend[g];
  int cnt = t - s;
  if (cnt < 0) cnt = 0;
  if (cnt > 1024) cnt = 1024;
  __shared__ float ew[1024];
  __shared__ float red[8];
  __shared__ float comb[256];
  int tid = threadIdx.x, wave = tid >> 6, lane = tid & 63;
  float qa = q[g * 128 + lane], qb = q[g * 128 + 64 + lane];
  for (int i = wave; i < cnt; i += 4) {
    int n = s + i;
    float a = agg[(size_t)n * 128 + lane] * qa + agg[(size_t)n * 128 + 64 + lane] * qb;
#pragma unroll
    for (int m = 1; m < 64; m <<= 1) a += __shfl_xor(a, m);
    if (lane == 0) ew[i] = a;
  }
  __syncthreads();
  float mx = -INFINITY;
  for (int i = tid; i < cnt; i += 256) mx = fmaxf(mx, ew[i]);
#pragma unroll
  for (int m = 1; m < 64; m <<= 1) mx = fmaxf(mx, __shfl_xor(mx, m));
  if (lane == 0) red[wave] = mx;
  __syncthreads();
  mx = fmaxf(fmaxf(red[0], red[1]), fmaxf(red[2], red[3]));
  float sm = 0.f;
  for (int i = tid; i < cnt; i += 256) sm += expf(ew[i] - mx);
#pragma unroll
  for (int m = 1; m < 64; m <<= 1) sm += __shfl_xor(sm, m);
  if (lane == 0) red[4 + wave] = sm;
  __syncthreads();
  sm = red[4] + red[5] + red[6] + red[7];
  float inv = (sm > 0.f) ? 1.f / sm : 0.f;
  __syncthreads();
  for (int i = tid; i < cnt; i += 256) ew[i] = expf(ew[i] - mx) * inv;
  __syncthreads();
  int d = tid & 127, half = tid >> 7;
  float acc = 0.f;
  for (int i = half; i < cnt; i += 2)
    acc = fmaf(ew[i], agg[(size_t)(s + i) * 128 + d], acc);
  comb[tid] = acc;
  __syncthreads();
  if (half == 0) {
    float r2 = acc + comb[128 + tid];
    q_star[(size_t)g * 256 + d] = q[(size_t)g * 128 + d];
    q_star[(size_t)g * 256 + 128 + d] = r2;
  }
}

__global__ void k_out(const float* __restrict__ qs, const float* __restrict__ W,
                      const float* __restrict__ bias, const float* __restrict__ pa,
                      float* __restrict__ out) {
  int idx = blockIdx.x * blockDim.x + threadIdx.x;
  if (idx >= N_B * N_DH) return;
  int b = idx >> 12, d = idx & 4095;
  float acc = bias[d];
  const float* q = qs + (size_t)b * 256;
  for (int k = 0; k < 256; ++k) acc = fmaf(q[k], W[(size_t)k * 4096 + d], acc);
  float a = pa[0];
  out[idx] = acc >= 0.f ? acc : a * acc;
}

// ---------------- workspace layout (float offsets) ----------------
enum : size_t {
  OFF_X0 = 0,
  OFF_HA = OFF_X0 + (size_t)N_N * 64,
  OFF_HB = OFF_HA + (size_t)N_N * 64,
  OFF_EF = OFF_HB + (size_t)N_N * 64,
  OFF_EE = OFF_EF + (size_t)N_E * 16,
  OFF_HAE = OFF_EE + (size_t)N_A * 16,   // ha_h fp16
  OFF_AMSG = OFF_HAE + (size_t)N_E * 64,
  OFF_HBE = OFF_AMSG + (size_t)N_E * 64, // hb_h fp16
  OFF_NACC = OFF_HBE + (size_t)N_E * 64,
  OFF_AGG = OFF_NACC + (size_t)N_N * 64,
  OFF_QSTAR = OFF_AGG + (size_t)N_N * 128,  // zero block starts here
  OFF_H0A = OFF_QSTAR + N_B * 256,
  OFF_H0B = OFF_H0A + N_B * 128,
  OFF_C0A = OFF_H0B + N_B * 128,
  OFF_C0B = OFF_C0A + N_B * 128,
  OFF_H1A = OFF_C0B + N_B * 128,
  OFF_H1B = OFF_H1A + N_B * 128,
  OFF_C1A = OFF_H1B + N_B * 128,
  OFF_C1B = OFF_C1A + N_B * 128,
  OFF_GSTART = OFF_C1B + N_B * 128,
  OFF_GEND = OFF_GSTART + N_B,
  OFF_TT_ANG = (OFF_GEND + N_B + 63) & ~(size_t)63,  // 1088*64 h16 = 34816 f
  OFF_TT_BOND = OFF_TT_ANG + 34816,
  OFF_WT_AU = OFF_TT_BOND + 34816,       // 4096 h16 = 2048 f
  OFF_WT_BU = OFF_WT_AU + 2048,
  OFF_W3T = OFF_WT_BU + 2048,            // 256*128 h16 = 16384 f
  WS_FLOATS = OFF_W3T + 16384
};

extern "C" void kernel_launch(void* const* d_in, const int* in_sizes, int n_in,
                              void* d_out, int out_size, void* d_ws, size_t ws_size,
                              hipStream_t stream) {
  (void)in_sizes; (void)n_in; (void)out_size; (void)ws_size;
  const float* na    = (const float*)d_in[0];
  const float* ea    = (const float*)d_in[1];
  const float* el    = (const float*)d_in[2];
  const float* ang   = (const float*)d_in[3];
  const int*   esrc  = (const int*)d_in[4];
  const int*   edst  = (const int*)d_in[5];
  const int*   asrc  = (const int*)d_in[6];
  const int*   adst  = (const int*)d_in[7];
  const int*   gid   = (const int*)d_in[8];
  const float* projW = (const float*)d_in[9];
  const float* projb = (const float*)d_in[10];
  const float* bondW = (const float*)d_in[11];
  const float* bondb = (const float*)d_in[12];
  const float* efW   = (const float*)d_in[13];
  const float* efb   = (const float*)d_in[14];
  const float* gnnb  = (const float*)d_in[15];
  const float* buW   = (const float*)d_in[16];
  const float* bub   = (const float*)d_in[17];
  const float* auW   = (const float*)d_in[18];
  const float* aub   = (const float*)d_in[19];
  const float* gWih  = (const float*)d_in[20];
  const float* gWhh  = (const float*)d_in[21];
  const float* gbih  = (const float*)d_in[22];
  const float* gbhh  = (const float*)d_in[23];
  const float* sWih0 = (const float*)d_in[24];
  const float* sWhh0 = (const float*)d_in[25];
  const float* sbih0 = (const float*)d_in[26];
  const float* sbhh0 = (const float*)d_in[27];
  const float* sWih1 = (const float*)d_in[28];
  const float* sWhh1 = (const float*)d_in[29];
  const float* sbih1 = (const float*)d_in[30];
  const float* sbhh1 = (const float*)d_in[31];
  const float* spW   = (const float*)d_in[32];
  const float* spb   = (const float*)d_in[33];
  const float* pa    = (const float*)d_in[34];
  float* out = (float*)d_out;
  float* ws = (float*)d_ws;

  float* x0   = ws + OFF_X0;
  float* hA   = ws + OFF_HA;
  float* hB   = ws + OFF_HB;
  float* ef   = ws + OFF_EF;
  float* ee   = ws + OFF_EE;
  h16*   ha_h = (h16*)(ws + OFF_HAE);
  float* amsg = ws + OFF_AMSG;
  h16*   hb_h = (h16*)(ws + OFF_HBE);
  float* nacc = ws + OFF_NACC;
  float* agg  = ws + OFF_AGG;
  float* qstar = ws + OFF_QSTAR;
  float* h0a = ws + OFF_H0A; float* h0b = ws + OFF_H0B;
  float* c0a = ws + OFF_C0A; float* c0b = ws + OFF_C0B;
  float* h1a = ws + OFF_H1A; float* h1b = ws + OFF_H1B;
  float* c1a = ws + OFF_C1A; float* c1b = ws + OFF_C1B;
  int* gstart = (int*)(ws + OFF_GSTART);
  int* gend   = (int*)(ws + OFF_GEND);
  h16* ttA = (h16*)(ws + OFF_TT_ANG);
  h16* ttB = (h16*)(ws + OFF_TT_BOND);
  h16* wtAU = (h16*)(ws + OFF_WT_AU);
  h16* wtBU = (h16*)(ws + OFF_WT_BU);
  h16* w3t  = (h16*)(ws + OFF_W3T);

  // ---- setup ----
  k_proj<<<(N_N * 64 + 255) / 256, 256, 0, stream>>>(na, projW, projb, x0);
  k_feat<<<(N_E + N_A + 255) / 256, 256, 0, stream>>>(ea, el, ang, asrc, ef, ee);
  k_prep<<<(PREP_B4 + 255) / 256, 256, 0, stream>>>(gWih, gWhh, efW, efb, bondW,
                                                    bondb, auW, buW, w3t, ttA, ttB,
                                                    wtAU, wtBU);
  hipMemsetAsync(gstart, 0x7f, N_B * sizeof(int), stream);
  hipMemsetAsync(gend, 0, N_B * sizeof(int), stream);
  k_bounds2<<<(N_N + 255) / 256, 256, 0, stream>>>(gid, gstart, gend);

  // ---- message-passing steps ----
  const int MLP_GX = (N_E + 127) / 128;
  const float* cur = x0;
  float* bufs[2] = {hA, hB};
  for (int s = 0; s < 4; ++s) {
    k_mfma_mlp<false><<<dim3(MLP_GX, 2), 256, 0, stream>>>(
        cur, esrc, wtAU, aub, nullptr, ha_h, N_E, (float4*)amsg, N_E * 64 / 4);
    k_mfma_mm<true><<<dim3((N_A + 127) / 128, 2), 256, 0, stream>>>(
        ha_h, asrc, ee, ttA, adst, amsg, N_A);
    k_mfma_mlp<true><<<dim3(MLP_GX, 2), 256, 0, stream>>>(
        cur, esrc, wtBU, bub, amsg, hb_h, N_E, (float4*)nacc, N_N * 64 / 4);
    k_mfma_mm<false><<<dim3(MLP_GX, 2), 256, 0, stream>>>(
        hb_h, nullptr, ef, ttB, edst, nacc, N_E);
    float* nxt = bufs[s & 1];
    k_gru2<<<(N_N + 63) / 64, 256, 0, stream>>>(nacc, gnnb, cur, w3t, gbih, gbhh,
                                                nxt, x0, agg, (s == 3) ? 1 : 0);
    cur = nxt;
  }

  // ---- Set2Set ----
  hipMemsetAsync(qstar, 0, (size_t)(N_B * 256 + 8 * N_B * 128) * sizeof(float), stream);
  float *h0i = h0a, *h0o = h0b, *c0i = c0a, *c0o = c0b;
  float *h1i = h1a, *h1o = h1b, *c1i = c1a, *c1o = c1b;
  for (int it = 0; it < 3; ++it) {
    k_lstm2<<<(N_B * 128 * 64 + 255) / 256, 256, 0, stream>>>(
        qstar, 256, h0i, c0i, sWih0, sWhh0, sbih0, sbhh0, h0o, c0o);
    k_lstm2<<<(N_B * 128 * 64 + 255) / 256, 256, 0, stream>>>(
        h0o, 128, h1i, c1i, sWih1, sWhh1, sbih1, sbhh1, h1o, c1o);
    k_pool2<<<N_B, 256, 0, stream>>>(agg, gstart, gend, h1o, qstar);
    float* tmp;
    tmp = h0i; h0i = h0o; h0o = tmp;
    tmp = c0i; c0i = c0o; c0o = tmp;
    tmp = h1i; h1i = h1o; h1o = tmp;
    tmp = c1i; c1i = c1o; c1o = tmp;
  }
  k_out<<<(N_B * N_DH + 255) / 256, 256, 0, stream>>>(qstar, spW, spb, pa, out);
}

// Round 6
// 414.361 us; speedup vs baseline: 6.5441x; 1.1102x over previous
//
#include <hip/hip_runtime.h>
#include <math.h>

#define N_N 8000
#define N_E 12000
#define N_A 48000
#define N_B 64
#define N_H 64
#define N_DH 4096

typedef _Float16 h16;
typedef __attribute__((ext_vector_type(8))) _Float16 h16x8;
typedef __attribute__((ext_vector_type(4))) float f32x4;

__device__ __forceinline__ float atomAddF(float* p, float v) {
  return __hip_atomic_fetch_add(p, v, __ATOMIC_RELAXED, __HIP_MEMORY_SCOPE_AGENT);
}
__device__ __forceinline__ float sigm(float x) { return 1.f / (1.f + expf(-x)); }

// ---------------- mega setup kernel ----------------
// block ranges: [0,2000) proj | [2000,2235) feat | [2235,2939) prep
//             | [2939,2971) bounds | [2971,4301) zero amsg0/nacc0/qstar-block
#define SB_PROJ 2000
#define SB_FEAT (SB_PROJ + 235)
#define SB_PREP (SB_FEAT + 704)
#define SB_BND  (SB_PREP + 32)
#define SB_ZERO (SB_BND + 1330)
#define PREP_B0 32768
#define PREP_B1 (PREP_B0 + 69632)
#define PREP_B2 (PREP_B1 + 69632)
#define PREP_B3 (PREP_B2 + 4096)
#define PREP_B4 (PREP_B3 + 4096)

__global__ __launch_bounds__(256) void k_setup(
    const float* __restrict__ na, const float* __restrict__ projW,
    const float* __restrict__ projb, const float* __restrict__ ea,
    const float* __restrict__ el, const float* __restrict__ ang,
    const int* __restrict__ asrc, const int* __restrict__ gid,
    const float* __restrict__ gWih, const float* __restrict__ gWhh,
    const float* __restrict__ efW, const float* __restrict__ efb,
    const float* __restrict__ bondW, const float* __restrict__ bondb,
    const float* __restrict__ auW, const float* __restrict__ buW,
    float* __restrict__ x0, float* __restrict__ ef, float* __restrict__ ee,
    int* __restrict__ gstart, int* __restrict__ gend,
    h16* __restrict__ W3t, h16* __restrict__ ttA, h16* __restrict__ ttB,
    h16* __restrict__ wtAU, h16* __restrict__ wtBU,
    float4* __restrict__ amsg0_4, float4* __restrict__ nacc0_4,
    float4* __restrict__ qz_4) {
  int bx = blockIdx.x, tid = threadIdx.x;
  if (bx < SB_PROJ) {
    int wid = bx * 4 + (tid >> 6);
    int lane = tid & 63;
    if (wid < N_N) {
      const float* row = na + (size_t)wid * 110;
      float acc = projb[lane];
      for (int k = 0; k < 110; ++k) acc = fmaf(row[k], projW[k * 64 + lane], acc);
      x0[(size_t)wid * 64 + lane] = fmaxf(acc, 0.f);
    }
  } else if (bx < SB_FEAT) {
    int i = (bx - SB_PROJ) * 256 + tid;
    const float g2 = (7.f / 4.f) * (7.f / 4.f);
    if (i < N_E) {
      int e = i;
      float x = el[e];
#pragma unroll
      for (int j = 0; j < 8; ++j) ef[e * 16 + j] = ea[e * 8 + j];
#pragma unroll
      for (int j = 0; j < 8; ++j) {
        float d = x - j * (4.f / 7.f);
        ef[e * 16 + 8 + j] = expf(-g2 * d * d);
      }
    } else if (i < N_E + N_A) {
      int a = i - N_E;
      const float PIf = 3.14159265358979323846f;
      float x = ang[a];
      float g1 = (7.f / PIf) * (7.f / PIf);
#pragma unroll
      for (int j = 0; j < 8; ++j) {
        float d = x - j * (PIf / 7.f);
        ee[a * 16 + j] = expf(-g1 * d * d);
      }
      float y = el[asrc[a]];
#pragma unroll
      for (int j = 0; j < 8; ++j) {
        float d = y - j * (4.f / 7.f);
        ee[a * 16 + 8 + j] = expf(-g2 * d * d);
      }
    }
  } else if (bx < SB_PREP) {
    int i = (bx - SB_FEAT) * 256 + tid;
    if (i < PREP_B0) {
      int col = i >> 7, k = i & 127;
      int grp = col >> 6, u = col & 63;
      float v;
      if (grp == 0) v = (k < 64) ? gWih[u * 64 + k] : gWhh[u * 64 + k - 64];
      else if (grp == 1) v = (k < 64) ? gWih[(64 + u) * 64 + k] : gWhh[(64 + u) * 64 + k - 64];
      else if (grp == 2) v = (k < 64) ? gWih[(128 + u) * 64 + k] : 0.f;
      else v = (k < 64) ? 0.f : gWhh[(128 + u) * 64 + k - 64];
      W3t[i] = (h16)v;
    } else if (i < PREP_B1) {
      int j = i - PREP_B0;
      int n = j >> 6, i2 = j & 63;
      int k = n >> 6, o = n & 63;
      float val = (k < 16) ? efW[(size_t)k * 4096 + i2 * 64 + o] : efb[i2 * 64 + o];
      ttA[j] = (h16)val;
    } else if (i < PREP_B2) {
      int j = i - PREP_B1;
      int n = j >> 6, i2 = j & 63;
      int k = n >> 6, o = n & 63;
      float val = (k < 16) ? bondW[(size_t)k * 4096 + i2 * 64 + o] : bondb[i2 * 64 + o];
      ttB[j] = (h16)val;
    } else if (i < PREP_B3) {
      int j = i - PREP_B2;
      int o = j >> 6, i2 = j & 63;
      wtAU[j] = (h16)auW[i2 * 64 + o];
    } else if (i < PREP_B4) {
      int j = i - PREP_B3;
      int o = j >> 6, i2 = j & 63;
      wtBU[j] = (h16)buW[i2 * 64 + o];
    }
  } else if (bx < SB_BND) {
    int n = (bx - SB_PREP) * 256 + tid;
    if (n < N_N) {
      int g = gid[n];
      if (n == 0 || gid[n - 1] != g) gstart[g] = n;
      if (n == N_N - 1 || gid[n + 1] != g) gend[g] = n + 1;
    }
  } else if (bx < SB_ZERO) {
    int i = (bx - SB_BND) * 256 + tid;
    float4 z = (float4){0.f, 0.f, 0.f, 0.f};
    if (i < 192000) amsg0_4[i] = z;
    else if (i < 320000) nacc0_4[i - 192000] = z;
    else if (i < 340480) qz_4[i - 320000] = z;
  }
}

// ---------------- fused MLP + per-item contraction + scatter ----------------
// Fragment maps (16x16x32 f16, verified family):
//   A[m,k]: m = lane&15, k = ks*32 + 8*(lane>>4) + j (j contiguous)
//   B[n,k]: n = lane&15, same k map (B^T storage [N][K])
//   D[m,n]: n = lane&15, m = (lane>>4)*4 + reg
//
// ANGLE: item a -> edge e=map[a]; v = relu(x[esrc[e]]@auW+aub)     (inline MLP)
// !ANGLE: item e;                v = relu(x[esrc[e]]@buW+bub)+amsg_in[e]
// then m[item,o] = sum_{kk<17} featx[item,kk]*(v @ Tt[kk*64+o,:]); atomic scatter.
// Wave = 32 items x 32 outs (blockIdx.y = o-half). Inline result goes through an
// XOR-swizzled per-wave LDS tile (D-frag -> A-frag relayout, no barrier needed).
template <bool ANGLE>
__global__ __launch_bounds__(256) void k_fused_mm(
    const float* __restrict__ xcur, const int* __restrict__ map,
    const int* __restrict__ esrc, const h16* __restrict__ WtU,
    const float* __restrict__ biasU, const float* __restrict__ amsg_in,
    const float* __restrict__ feat, const h16* __restrict__ Tt,
    const int* __restrict__ dst, float* __restrict__ outacc, int T,
    float4* __restrict__ zbuf, int zcount4) {
  if (zbuf && blockIdx.y == 0) {
    int stride = gridDim.x * 256;
    for (int i = blockIdx.x * 256 + threadIdx.x; i < zcount4; i += stride)
      zbuf[i] = (float4){0.f, 0.f, 0.f, 0.f};
  }
  __shared__ h16 haT[4][2048];     // per-wave 32x64 fp16 tile (XOR-swizzled)
  __shared__ float f_lds[128 * 17];
  __shared__ int dst_lds[128];
  int tid = threadIdx.x;
  int base = blockIdx.x * 128;
  int oc = blockIdx.y;
  for (int e = tid; e < 128 * 16; e += 256) {
    int il = e >> 4, k = e & 15;
    int g = base + il;
    if (g >= T) g = T - 1;
    f_lds[il * 17 + k] = feat[(size_t)g * 16 + k];
  }
  if (tid < 128) {
    int g = base + tid;
    if (g >= T) g = T - 1;
    dst_lds[tid] = dst[g];
  }
  __syncthreads();

  int wave = tid >> 6, lane = tid & 63;
  int l15 = lane & 15, lq = lane >> 4;
  int ibl = wave * 32;
  int ib0 = base + ibl;
  h16* myT = haT[wave];

  // ---- inline 64x64 MLP ----
  {
    h16x8 xafr[2][2];
#pragma unroll
    for (int s = 0; s < 2; ++s) {
      int item = ib0 + s * 16 + l15;
      if (item >= T) item = T - 1;
      int e = ANGLE ? map[item] : item;
      const float* vp = xcur + (size_t)esrc[e] * 64;
#pragma unroll
      for (int ks = 0; ks < 2; ++ks) {
        const float4* p = (const float4*)(vp + ks * 32 + 8 * lq);
        float4 v0 = p[0], v1 = p[1];
        h16x8 a;
        a[0] = (h16)v0.x; a[1] = (h16)v0.y; a[2] = (h16)v0.z; a[3] = (h16)v0.w;
        a[4] = (h16)v1.x; a[5] = (h16)v1.y; a[6] = (h16)v1.z; a[7] = (h16)v1.w;
        xafr[s][ks] = a;
      }
    }
    f32x4 aU[2][4];
#pragma unroll
    for (int s = 0; s < 2; ++s)
#pragma unroll
      for (int nt = 0; nt < 4; ++nt) aU[s][nt] = (f32x4){0.f, 0.f, 0.f, 0.f};
#pragma unroll
    for (int nt = 0; nt < 4; ++nt) {
#pragma unroll
      for (int ks = 0; ks < 2; ++ks) {
        h16x8 b = *(const h16x8*)(WtU + (size_t)(nt * 16 + l15) * 64 + ks * 32 + 8 * lq);
#pragma unroll
        for (int s = 0; s < 2; ++s)
          aU[s][nt] = __builtin_amdgcn_mfma_f32_16x16x32_f16(xafr[s][ks], b, aU[s][nt], 0, 0, 0);
      }
    }
    // epilogue: relu(+bias)(+amsg) -> swizzled LDS tile
#pragma unroll
    for (int s = 0; s < 2; ++s) {
#pragma unroll
      for (int nt = 0; nt < 4; ++nt) {
        int o = nt * 16 + l15;
        float bo = biasU[o];
#pragma unroll
        for (int r = 0; r < 4; ++r) {
          int row = s * 16 + lq * 4 + r;
          float val = fmaxf(aU[s][nt][r] + bo, 0.f);
          if (!ANGLE) {
            int item = ib0 + row;
            if (item >= T) item = T - 1;
            val += amsg_in[(size_t)item * 64 + o];
          }
          int idx = (((row * 64 + o) << 1) ^ ((row & 7) << 4)) >> 1;
          myT[idx] = (h16)val;
        }
      }
    }
  }

  // ---- A-frags from swizzled LDS (same-wave RAW: in-order LDS, no barrier) ----
  h16x8 afr[2][2];
#pragma unroll
  for (int s = 0; s < 2; ++s) {
#pragma unroll
    for (int ks = 0; ks < 2; ++ks) {
      int row = s * 16 + l15;
      int byte = ((row * 64 + ks * 32 + 8 * lq) << 1) ^ ((row & 7) << 4);
      afr[s][ks] = *(const h16x8*)((const char*)myT + byte);
    }
  }

  f32x4 acc[2][2];
#pragma unroll
  for (int s = 0; s < 2; ++s)
#pragma unroll
    for (int nt = 0; nt < 2; ++nt) acc[s][nt] = (f32x4){0.f, 0.f, 0.f, 0.f};

  for (int kk = 0; kk < 16; ++kk) {
    h16x8 bfr[2][2];
#pragma unroll
    for (int nt = 0; nt < 2; ++nt)
#pragma unroll
      for (int ks = 0; ks < 2; ++ks)
        bfr[nt][ks] = *(const h16x8*)(Tt + (size_t)(kk * 64 + (oc * 2 + nt) * 16 + l15) * 64 +
                                      ks * 32 + 8 * lq);
    h16x8 a2[2][2];
#pragma unroll
    for (int s = 0; s < 2; ++s) {
      h16 fs = (h16)f_lds[(ibl + s * 16 + l15) * 17 + kk];
      a2[s][0] = afr[s][0] * fs;
      a2[s][1] = afr[s][1] * fs;
    }
#pragma unroll
    for (int s = 0; s < 2; ++s)
#pragma unroll
      for (int nt = 0; nt < 2; ++nt)
#pragma unroll
        for (int ks = 0; ks < 2; ++ks)
          acc[s][nt] = __builtin_amdgcn_mfma_f32_16x16x32_f16(a2[s][ks], bfr[nt][ks],
                                                              acc[s][nt], 0, 0, 0);
  }
  {  // bias row (kk=16, featx=1)
    h16x8 bfr[2][2];
#pragma unroll
    for (int nt = 0; nt < 2; ++nt)
#pragma unroll
      for (int ks = 0; ks < 2; ++ks)
        bfr[nt][ks] = *(const h16x8*)(Tt + (size_t)(16 * 64 + (oc * 2 + nt) * 16 + l15) * 64 +
                                      ks * 32 + 8 * lq);
#pragma unroll
    for (int s = 0; s < 2; ++s)
#pragma unroll
      for (int nt = 0; nt < 2; ++nt)
#pragma unroll
        for (int ks = 0; ks < 2; ++ks)
          acc[s][nt] = __builtin_amdgcn_mfma_f32_16x16x32_f16(afr[s][ks], bfr[nt][ks],
                                                              acc[s][nt], 0, 0, 0);
  }

#pragma unroll
  for (int s = 0; s < 2; ++s) {
#pragma unroll
    for (int r = 0; r < 4; ++r) {
      int il = ibl + s * 16 + lq * 4 + r;
      int item = base + il;
      if (item < T) {
        float* op = outacc + (size_t)dst_lds[il] * 64;
#pragma unroll
        for (int nt = 0; nt < 2; ++nt)
          atomAddF(op + (oc * 2 + nt) * 16 + l15, acc[s][nt][r]);
      }
    }
  }
}

// MFMA GRU: gates = [relu(nacc+gnnb) | h] @ W3t^T (256 cols), epilogue applies GRU.
// Wave = 16 nodes; block = 4 waves. Optionally writes agg rows; zeroes zbuf.
__global__ __launch_bounds__(256) void k_gru2(
    const float* __restrict__ nacc, const float* __restrict__ gnnb,
    const float* __restrict__ h, const h16* __restrict__ W3t,
    const float* __restrict__ gbih, const float* __restrict__ gbhh,
    float* __restrict__ hout, const float* __restrict__ x0,
    float* __restrict__ agg, int wagg, float4* __restrict__ zbuf, int zcount4) {
  if (zbuf) {
    int stride = gridDim.x * 256;
    for (int i = blockIdx.x * 256 + threadIdx.x; i < zcount4; i += stride)
      zbuf[i] = (float4){0.f, 0.f, 0.f, 0.f};
  }
  int tid = threadIdx.x, wave = tid >> 6, lane = tid & 63;
  int l15 = lane & 15, lq = lane >> 4;
  int ib0 = blockIdx.x * 64 + wave * 16;
  int nodeA = ib0 + l15;
  if (nodeA >= N_N) nodeA = N_N - 1;

  h16x8 afr[4];
#pragma unroll
  for (int ks = 0; ks < 2; ++ks) {
    const float4* p = (const float4*)(nacc + (size_t)nodeA * 64 + ks * 32 + 8 * lq);
    const float4* gp = (const float4*)(gnnb + ks * 32 + 8 * lq);
    float4 v0 = p[0], v1 = p[1], g0 = gp[0], g1 = gp[1];
    h16x8 a;
    a[0] = (h16)fmaxf(v0.x + g0.x, 0.f); a[1] = (h16)fmaxf(v0.y + g0.y, 0.f);
    a[2] = (h16)fmaxf(v0.z + g0.z, 0.f); a[3] = (h16)fmaxf(v0.w + g0.w, 0.f);
    a[4] = (h16)fmaxf(v1.x + g1.x, 0.f); a[5] = (h16)fmaxf(v1.y + g1.y, 0.f);
    a[6] = (h16)fmaxf(v1.z + g1.z, 0.f); a[7] = (h16)fmaxf(v1.w + g1.w, 0.f);
    afr[ks] = a;
  }
#pragma unroll
  for (int ks = 0; ks < 2; ++ks) {
    const float4* p = (const float4*)(h + (size_t)nodeA * 64 + ks * 32 + 8 * lq);
    float4 v0 = p[0], v1 = p[1];
    h16x8 a;
    a[0] = (h16)v0.x; a[1] = (h16)v0.y; a[2] = (h16)v0.z; a[3] = (h16)v0.w;
    a[4] = (h16)v1.x; a[5] = (h16)v1.y; a[6] = (h16)v1.z; a[7] = (h16)v1.w;
    afr[2 + ks] = a;
  }

  f32x4 acc[16];
#pragma unroll
  for (int nt = 0; nt < 16; ++nt) acc[nt] = (f32x4){0.f, 0.f, 0.f, 0.f};
#pragma unroll
  for (int nt = 0; nt < 16; ++nt) {
#pragma unroll
    for (int ks = 0; ks < 4; ++ks) {
      if (nt >= 8 && nt < 12 && ks >= 2) continue;
      if (nt >= 12 && ks < 2) continue;
      h16x8 b = *(const h16x8*)(W3t + (size_t)(nt * 16 + l15) * 128 + ks * 32 + 8 * lq);
      acc[nt] = __builtin_amdgcn_mfma_f32_16x16x32_f16(afr[ks], b, acc[nt], 0, 0, 0);
    }
  }

#pragma unroll
  for (int nt0 = 0; nt0 < 4; ++nt0) {
    int u = nt0 * 16 + l15;
    float br = gbih[u] + gbhh[u];
    float bz = gbih[64 + u] + gbhh[64 + u];
    float bin_ = gbih[128 + u];
    float bhn = gbhh[128 + u];
#pragma unroll
    for (int r = 0; r < 4; ++r) {
      int node = ib0 + lq * 4 + r;
      if (node < N_N) {
        float rr = sigm(acc[nt0][r] + br);
        float zz = sigm(acc[nt0 + 4][r] + bz);
        float nn = tanhf(acc[nt0 + 8][r] + bin_ + rr * (acc[nt0 + 12][r] + bhn));
        float hv = h[(size_t)node * 64 + u];
        float val = (1.f - zz) * nn + zz * hv;
        hout[(size_t)node * 64 + u] = val;
        if (wagg) {
          agg[(size_t)node * 128 + u] = val;
          agg[(size_t)node * 128 + 64 + u] = x0[(size_t)node * 64 + u];
        }
      }
    }
  }
}

// ---------------- Set2Set ----------------

__global__ __launch_bounds__(256) void k_lstm2(
    const float* __restrict__ x, int xdim,
    const float* __restrict__ hin, const float* __restrict__ cin,
    const float* __restrict__ Wih, const float* __restrict__ Whh,
    const float* __restrict__ bih, const float* __restrict__ bhh,
    float* __restrict__ hout, float* __restrict__ cout) {
  int w = (blockIdx.x * blockDim.x + threadIdx.x) >> 6;
  int lane = threadIdx.x & 63;
  if (w >= N_B * 128) return;
  int b = w >> 7, u = w & 127;
  float a0 = 0.f, a1 = 0.f, a2 = 0.f, a3 = 0.f;
  const float* xr = x + (size_t)b * xdim;
  for (int k = lane; k < xdim; k += 64) {
    float xv = xr[k];
    a0 = fmaf(xv, Wih[(size_t)u * xdim + k], a0);
    a1 = fmaf(xv, Wih[(size_t)(128 + u) * xdim + k], a1);
    a2 = fmaf(xv, Wih[(size_t)(256 + u) * xdim + k], a2);
    a3 = fmaf(xv, Wih[(size_t)(384 + u) * xdim + k], a3);
  }
  const float* hr = hin + (size_t)b * 128;
#pragma unroll
  for (int k0 = 0; k0 < 128; k0 += 64) {
    int k = k0 + lane;
    float hv = hr[k];
    a0 = fmaf(hv, Whh[(size_t)u * 128 + k], a0);
    a1 = fmaf(hv, Whh[(size_t)(128 + u) * 128 + k], a1);
    a2 = fmaf(hv, Whh[(size_t)(256 + u) * 128 + k], a2);
    a3 = fmaf(hv, Whh[(size_t)(384 + u) * 128 + k], a3);
  }
#pragma unroll
  for (int m = 1; m < 64; m <<= 1) {
    a0 += __shfl_xor(a0, m);
    a1 += __shfl_xor(a1, m);
    a2 += __shfl_xor(a2, m);
    a3 += __shfl_xor(a3, m);
  }
  if (lane == 0) {
    float gi = a0 + bih[u] + bhh[u];
    float gf = a1 + bih[128 + u] + bhh[128 + u];
    float gg = a2 + bih[256 + u] + bhh[256 + u];
    float go = a3 + bih[384 + u] + bhh[384 + u];
    float c2 = sigm(gf) * cin[(size_t)b * 128 + u] + sigm(gi) * tanhf(gg);
    hout[(size_t)b * 128 + u] = sigm(go) * tanhf(c2);
    cout[(size_t)b * 128 + u] = c2;
  }
}

__global__ __launch_bounds__(256) void k_pool2(
    const float* __restrict__ agg, const int* __restrict__ gstart,
    const int* __restrict__ gend, const float* __restrict__ q,
    float* __restrict__ q_star) {
  int g = blockIdx.x;
  int s = gstart[g], t = gend[g];
  int cnt = t - s;
  if (cnt < 0) cnt = 0;
  if (cnt > 1024) cnt = 1024;
  __shared__ float ew[1024];
  __shared__ float red[8];
  __shared__ float comb[256];
  int tid = threadIdx.x, wave = tid >> 6, lane = tid & 63;
  float qa = q[g * 128 + lane], qb = q[g * 128 + 64 + lane];
  for (int i = wave; i < cnt; i += 4) {
    int n = s + i;
    float a = agg[(size_t)n * 128 + lane] * qa + agg[(size_t)n * 128 + 64 + lane] * qb;
#pragma unroll
    for (int m = 1; m < 64; m <<= 1) a += __shfl_xor(a, m);
    if (lane == 0) ew[i] = a;
  }
  __syncthreads();
  float mx = -INFINITY;
  for (int i = tid; i < cnt; i += 256) mx = fmaxf(mx, ew[i]);
#pragma unroll
  for (int m = 1; m < 64; m <<= 1) mx = fmaxf(mx, __shfl_xor(mx, m));
  if (lane == 0) red[wave] = mx;
  __syncthreads();
  mx = fmaxf(fmaxf(red[0], red[1]), fmaxf(red[2], red[3]));
  float sm = 0.f;
  for (int i = tid; i < cnt; i += 256) sm += expf(ew[i] - mx);
#pragma unroll
  for (int m = 1; m < 64; m <<= 1) sm += __shfl_xor(sm, m);
  if (lane == 0) red[4 + wave] = sm;
  __syncthreads();
  sm = red[4] + red[5] + red[6] + red[7];
  float inv = (sm > 0.f) ? 1.f / sm : 0.f;
  __syncthreads();
  for (int i = tid; i < cnt; i += 256) ew[i] = expf(ew[i] - mx) * inv;
  __syncthreads();
  int d = tid & 127, half = tid >> 7;
  float acc = 0.f;
  for (int i = half; i < cnt; i += 2)
    acc = fmaf(ew[i], agg[(size_t)(s + i) * 128 + d], acc);
  comb[tid] = acc;
  __syncthreads();
  if (half == 0) {
    float r2 = acc + comb[128 + tid];
    q_star[(size_t)g * 256 + d] = q[(size_t)g * 128 + d];
    q_star[(size_t)g * 256 + 128 + d] = r2;
  }
}

__global__ void k_out(const float* __restrict__ qs, const float* __restrict__ W,
                      const float* __restrict__ bias, const float* __restrict__ pa,
                      float* __restrict__ out) {
  int idx = blockIdx.x * blockDim.x + threadIdx.x;
  if (idx >= N_B * N_DH) return;
  int b = idx >> 12, d = idx & 4095;
  float acc = bias[d];
  const float* q = qs + (size_t)b * 256;
  for (int k = 0; k < 256; ++k) acc = fmaf(q[k], W[(size_t)k * 4096 + d], acc);
  float a = pa[0];
  out[idx] = acc >= 0.f ? acc : a * acc;
}

// ---------------- workspace layout (float offsets) ----------------
enum : size_t {
  OFF_X0 = 0,
  OFF_HA = OFF_X0 + (size_t)N_N * 64,
  OFF_HB = OFF_HA + (size_t)N_N * 64,
  OFF_EF = OFF_HB + (size_t)N_N * 64,
  OFF_EE = OFF_EF + (size_t)N_E * 16,
  OFF_AMSG0 = OFF_EE + (size_t)N_A * 16,
  OFF_AMSG1 = OFF_AMSG0 + (size_t)N_E * 64,
  OFF_NACC0 = OFF_AMSG1 + (size_t)N_E * 64,
  OFF_NACC1 = OFF_NACC0 + (size_t)N_N * 64,
  OFF_AGG = OFF_NACC1 + (size_t)N_N * 64,
  OFF_QSTAR = OFF_AGG + (size_t)N_N * 128,  // zero block: qstar + 8 state bufs
  OFF_H0A = OFF_QSTAR + N_B * 256,
  OFF_H0B = OFF_H0A + N_B * 128,
  OFF_C0A = OFF_H0B + N_B * 128,
  OFF_C0B = OFF_C0A + N_B * 128,
  OFF_H1A = OFF_C0B + N_B * 128,
  OFF_H1B = OFF_H1A + N_B * 128,
  OFF_C1A = OFF_H1B + N_B * 128,
  OFF_C1B = OFF_C1A + N_B * 128,
  OFF_GSTART = OFF_C1B + N_B * 128,  // gstart(64) then gend(64): one memset
  OFF_GEND = OFF_GSTART + N_B,
  OFF_TT_ANG = (OFF_GEND + N_B + 63) & ~(size_t)63,
  OFF_TT_BOND = OFF_TT_ANG + 34816,
  OFF_WT_AU = OFF_TT_BOND + 34816,
  OFF_WT_BU = OFF_WT_AU + 2048,
  OFF_W3T = OFF_WT_BU + 2048,
  WS_FLOATS = OFF_W3T + 16384
};

extern "C" void kernel_launch(void* const* d_in, const int* in_sizes, int n_in,
                              void* d_out, int out_size, void* d_ws, size_t ws_size,
                              hipStream_t stream) {
  (void)in_sizes; (void)n_in; (void)out_size; (void)ws_size;
  const float* na    = (const float*)d_in[0];
  const float* ea    = (const float*)d_in[1];
  const float* el    = (const float*)d_in[2];
  const float* ang   = (const float*)d_in[3];
  const int*   esrc  = (const int*)d_in[4];
  const int*   edst  = (const int*)d_in[5];
  const int*   asrc  = (const int*)d_in[6];
  const int*   adst  = (const int*)d_in[7];
  const int*   gid   = (const int*)d_in[8];
  const float* projW = (const float*)d_in[9];
  const float* projb = (const float*)d_in[10];
  const float* bondW = (const float*)d_in[11];
  const float* bondb = (const float*)d_in[12];
  const float* efW   = (const float*)d_in[13];
  const float* efb   = (const float*)d_in[14];
  const float* gnnb  = (const float*)d_in[15];
  const float* buW   = (const float*)d_in[16];
  const float* bub   = (const float*)d_in[17];
  const float* auW   = (const float*)d_in[18];
  const float* aub   = (const float*)d_in[19];
  const float* gWih  = (const float*)d_in[20];
  const float* gWhh  = (const float*)d_in[21];
  const float* gbih  = (const float*)d_in[22];
  const float* gbhh  = (const float*)d_in[23];
  const float* sWih0 = (const float*)d_in[24];
  const float* sWhh0 = (const float*)d_in[25];
  const float* sbih0 = (const float*)d_in[26];
  const float* sbhh0 = (const float*)d_in[27];
  const float* sWih1 = (const float*)d_in[28];
  const float* sWhh1 = (const float*)d_in[29];
  const float* sbih1 = (const float*)d_in[30];
  const float* sbhh1 = (const float*)d_in[31];
  const float* spW   = (const float*)d_in[32];
  const float* spb   = (const float*)d_in[33];
  const float* pa    = (const float*)d_in[34];
  float* out = (float*)d_out;
  float* ws = (float*)d_ws;

  float* x0    = ws + OFF_X0;
  float* hA    = ws + OFF_HA;
  float* hB    = ws + OFF_HB;
  float* ef    = ws + OFF_EF;
  float* ee    = ws + OFF_EE;
  float* amsg0 = ws + OFF_AMSG0;
  float* amsg1 = ws + OFF_AMSG1;
  float* nacc0 = ws + OFF_NACC0;
  float* nacc1 = ws + OFF_NACC1;
  float* agg   = ws + OFF_AGG;
  float* qstar = ws + OFF_QSTAR;
  float* h0a = ws + OFF_H0A; float* h0b = ws + OFF_H0B;
  float* c0a = ws + OFF_C0A; float* c0b = ws + OFF_C0B;
  float* h1a = ws + OFF_H1A; float* h1b = ws + OFF_H1B;
  float* c1a = ws + OFF_C1A; float* c1b = ws + OFF_C1B;
  int* gstart = (int*)(ws + OFF_GSTART);
  h16* ttA = (h16*)(ws + OFF_TT_ANG);
  h16* ttB = (h16*)(ws + OFF_TT_BOND);
  h16* wtAU = (h16*)(ws + OFF_WT_AU);
  h16* wtBU = (h16*)(ws + OFF_WT_BU);
  h16* w3t  = (h16*)(ws + OFF_W3T);

  // ---- setup: one memset (gstart|gend, 0x7f => absent graphs get cnt==0) + mega-kernel
  hipMemsetAsync(gstart, 0x7f, 2 * N_B * sizeof(int), stream);
  k_setup<<<SB_ZERO, 256, 0, stream>>>(
      na, projW, projb, ea, el, ang, asrc, gid, gWih, gWhh, efW, efb, bondW, bondb,
      auW, buW, x0, ef, ee, gstart, gstart + N_B, w3t, ttA, ttB, wtAU, wtBU,
      (float4*)amsg0, (float4*)nacc0, (float4*)qstar);

  // ---- message-passing steps (3 dispatches per step) ----
  const float* cur = x0;
  float* bufs[2] = {hA, hB};
  float* amsgs[2] = {amsg0, amsg1};
  float* naccs[2] = {nacc0, nacc1};
  for (int s = 0; s < 4; ++s) {
    float* amsg_c = amsgs[s & 1];
    float* amsg_o = amsgs[(s + 1) & 1];
    float* nacc_c = naccs[s & 1];
    float* nacc_o = naccs[(s + 1) & 1];
    // angle: inline ha + contraction + scatter into amsg_c
    k_fused_mm<true><<<dim3((N_A + 127) / 128, 2), 256, 0, stream>>>(
        cur, asrc, esrc, wtAU, aub, nullptr, ee, ttA, adst, amsg_c, N_A,
        nullptr, 0);
    // bond: inline hb(+amsg_c) + contraction + scatter into nacc_c; zeroes amsg_o
    k_fused_mm<false><<<dim3((N_E + 127) / 128, 2), 256, 0, stream>>>(
        cur, nullptr, esrc, wtBU, bub, amsg_c, ef, ttB, edst, nacc_c, N_E,
        (float4*)amsg_o, N_E * 64 / 4);
    // GRU; zeroes nacc_o
    float* nxt = bufs[s & 1];
    k_gru2<<<(N_N + 63) / 64, 256, 0, stream>>>(nacc_c, gnnb, cur, w3t, gbih, gbhh,
                                                nxt, x0, agg, (s == 3) ? 1 : 0,
                                                (float4*)nacc_o, N_N * 64 / 4);
    cur = nxt;
  }

  // ---- Set2Set (qstar/h/c zeroed by k_setup) ----
  float *h0i = h0a, *h0o = h0b, *c0i = c0a, *c0o = c0b;
  float *h1i = h1a, *h1o = h1b, *c1i = c1a, *c1o = c1b;
  for (int it = 0; it < 3; ++it) {
    k_lstm2<<<(N_B * 128 * 64 + 255) / 256, 256, 0, stream>>>(
        qstar, 256, h0i, c0i, sWih0, sWhh0, sbih0, sbhh0, h0o, c0o);
    k_lstm2<<<(N_B * 128 * 64 + 255) / 256, 256, 0, stream>>>(
        h0o, 128, h1i, c1i, sWih1, sWhh1, sbih1, sbhh1, h1o, c1o);
    k_pool2<<<N_B, 256, 0, stream>>>(agg, gstart, gstart + N_B, h1o, qstar);
    float* tmp;
    tmp = h0i; h0i = h0o; h0o = tmp;
    tmp = c0i; c0i = c0o; c0o = tmp;
    tmp = h1i; h1i = h1o; h1o = tmp;
    tmp = c1i; c1i = c1o; c1o = tmp;
  }
  k_out<<<(N_B * N_DH + 255) / 256, 256, 0, stream>>>(qstar, spW, spb, pa, out);
}